// Round 4
// baseline (1230.172 us; speedup 1.0000x reference)
//
#include <hip/hip_runtime.h>

// VectorQuantizer: N=32768 tokens, K=8192 codes, D=256, fp32 in/out.
// Outputs (concat, float): z_q_ste[32768*256], idx[32768] (as float), loss[1].
// R4: stage-1 fp16 1-term MFMA GEMM (error ~5e-4) + top-2 gap flagging;
// flagged tokens (gap < 0.025, ~5%) re-scored by gathered bf16 3-term GEMM
// over all codes; sub-flagged (gap < 1e-3) get exact fp32 rescore.

#define N_TOK   32768
#define KC      8192
#define DD      256
#define D4      64
#define SPLITS  8
#define KSPLIT  1024
#define MT      128
#define NT      128
#define EPS1    0.025f
#define EPS2    1e-3f
#define FLAG_CAP 8192
#define CAP2     4096
#define ASTR    40

typedef __bf16    bf16x8 __attribute__((ext_vector_type(8)));
typedef _Float16  f16x8  __attribute__((ext_vector_type(8)));
typedef _Float16  f16x4  __attribute__((ext_vector_type(4)));
typedef float     f32x4  __attribute__((ext_vector_type(4)));

#define GLL(gp, lp) __builtin_amdgcn_global_load_lds(                                   \
    (const __attribute__((address_space(1))) void*)(unsigned long long)(uintptr_t)(gp), \
    (__attribute__((address_space(3))) void*)(unsigned)(uintptr_t)(lp), 16, 0, 0)

#define PK(a, b, HO, LO) do {                                   \
    unsigned ua = __float_as_uint(a), ub = __float_as_uint(b);  \
    unsigned ham = ua & 0xFFFF0000u, hbm = ub & 0xFFFF0000u;    \
    float la = (a) - __uint_as_float(ham);                      \
    float lb = (b) - __uint_as_float(hbm);                      \
    HO = (ua >> 16) | hbm;                                      \
    LO = (__float_as_uint(la) >> 16) | (__float_as_uint(lb) & 0xFFFF0000u); \
} while (0)

// ---------------- kernel 1: code norms + cb->f16 + zero accumulators ----------------
__global__ __launch_bounds__(256)
void k_cnorm(const float* __restrict__ cb, float* __restrict__ cnorm,
             double* __restrict__ accum, int* __restrict__ flagc,
             int* __restrict__ flagc2, _Float16* __restrict__ cbf16) {
    if (blockIdx.x == 0 && threadIdx.x == 0) { *accum = 0.0; *flagc = 0; *flagc2 = 0; }
    const int gid  = blockIdx.x * 256 + threadIdx.x;
    const int code = gid >> 6;
    const int lane = threadIdx.x & 63;
    if (code < KC) {
        float4 v = ((const float4*)cb)[code * D4 + lane];
        if (cbf16) {
            f16x4 h;
            h[0] = (_Float16)v.x; h[1] = (_Float16)v.y;
            h[2] = (_Float16)v.z; h[3] = (_Float16)v.w;
            *(f16x4*)(cbf16 + (size_t)code * DD + lane * 4) = h;
        }
        float s = v.x*v.x + v.y*v.y + v.z*v.z + v.w*v.w;
        #pragma unroll
        for (int off = 32; off > 0; off >>= 1) s += __shfl_down(s, off);
        if (lane == 0) cnorm[code] = s;
    }
}

// ---------------- kernel 2: z_e -> fp16 ----------------
__global__ __launch_bounds__(256)
void k_convert_ze(const float* __restrict__ src, _Float16* __restrict__ dst, int n8) {
    int t = blockIdx.x * 256 + threadIdx.x;
    if (t >= n8) return;
    const float4* s = (const float4*)src;
    float4 v0 = s[2 * t], v1 = s[2 * t + 1];
    f16x8 h;
    h[0] = (_Float16)v0.x; h[1] = (_Float16)v0.y; h[2] = (_Float16)v0.z; h[3] = (_Float16)v0.w;
    h[4] = (_Float16)v1.x; h[5] = (_Float16)v1.y; h[6] = (_Float16)v1.z; h[7] = (_Float16)v1.w;
    ((f16x8*)dst)[t] = h;
}

// ---------------- kernel 3: stage-1 fp16 1-term MFMA GEMM + top-2 ----------------
__global__ __launch_bounds__(256, 3)
void k_argmin_f16(const _Float16* __restrict__ zef, const _Float16* __restrict__ cbf,
                  const float* __restrict__ cnorm, float4* __restrict__ partial) {
    // A,B tiles: 128 rows x 64 f16 (128 B/row), XOR swizzle g' = g ^ (row&7)
    __shared__ __align__(16) char smem[32768];
    char* Ab = smem;
    char* Bb = smem + 16384;

    const int tid  = threadIdx.x;
    const int lane = tid & 63;
    const int wid  = tid >> 6;
    const int cl   = lane & 15;
    const int kq   = lane >> 4;
    const int wm   = (wid & 1) * 64;
    const int wn   = (wid >> 1) * 64;
    const int m0   = blockIdx.x * MT;
    const int split = blockIdx.y;

    // staging: slot = j*256 + wid*64 + lane; row = slot>>3, g' = slot&7, g = g'^(row&7)
    unsigned aoffs[4], boffs[4];
    #pragma unroll
    for (int j = 0; j < 4; ++j) {
        int slot = j * 256 + wid * 64 + lane;
        int r = slot >> 3;
        int g = (slot & 7) ^ (r & 7);
        aoffs[j] = (unsigned)(m0 + r) * 512u + (unsigned)g * 16u;
        boffs[j] = (unsigned)(split * KSPLIT + r) * 512u + (unsigned)g * 16u;
    }
    const int ldsw = wid * 1024;

    // fragment byte offsets (k-step s=0); s=1 is ^64
    int ar[4], br[4];
    #pragma unroll
    for (int mt = 0; mt < 4; ++mt) { int r = wm + mt*16 + cl; ar[mt] = r*128 + ((kq ^ (r & 7)) << 4); }
    #pragma unroll
    for (int nt = 0; nt < 4; ++nt) { int r = wn + nt*16 + cl; br[nt] = r*128 + ((kq ^ (r & 7)) << 4); }

    float best[16], sec[16]; int bidx[16];
    #pragma unroll
    for (int s = 0; s < 16; ++s) { best[s] = 3.4e38f; sec[s] = 3.4e38f; bidx[s] = 0; }

    for (int ch = 0; ch < 8; ++ch) {                 // 8 N-tiles of 128 codes
        const int c0 = split * KSPLIT + ch * NT;
        f32x4 acc[4][4];
        #pragma unroll
        for (int mt = 0; mt < 4; ++mt)
            #pragma unroll
            for (int nt = 0; nt < 4; ++nt)
                acc[mt][nt] = (f32x4){0.f, 0.f, 0.f, 0.f};

        for (int ks = 0; ks < 4; ++ks) {             // BK=64: 4 slabs of K
            __syncthreads();
            const unsigned ko = (unsigned)(ks << 7);
            #pragma unroll
            for (int j = 0; j < 4; ++j) {
                GLL((const char*)zef + aoffs[j] + ko,                 Ab + j * 4096 + ldsw);
                GLL((const char*)cbf + boffs[j] + ch * 65536u + ko,   Bb + j * 4096 + ldsw);
            }
            __syncthreads();
            #pragma unroll
            for (int s = 0; s < 2; ++s) {            // two K=32 mfma steps in the slab
                const int sx = s << 6;
                f16x8 b[4];
                #pragma unroll
                for (int nt = 0; nt < 4; ++nt) b[nt] = *(const f16x8*)(Bb + (br[nt] ^ sx));
                #pragma unroll
                for (int mt = 0; mt < 4; ++mt) {
                    f16x8 a = *(const f16x8*)(Ab + (ar[mt] ^ sx));
                    #pragma unroll
                    for (int nt = 0; nt < 4; ++nt)
                        acc[mt][nt] = __builtin_amdgcn_mfma_f32_16x16x32_f16(a, b[nt], acc[mt][nt], 0, 0, 0);
                }
            }
        }
        #pragma unroll
        for (int nt = 0; nt < 4; ++nt) {
            const int code = c0 + wn + nt * 16 + cl;
            const float cn = cnorm[code];
            #pragma unroll
            for (int mt = 0; mt < 4; ++mt)
                #pragma unroll
                for (int r = 0; r < 4; ++r) {
                    float dist = fmaf(-2.f, acc[mt][nt][r], cn);
                    int s = mt * 4 + r;
                    bool lt = dist < best[s];
                    sec[s] = lt ? best[s] : fminf(sec[s], dist);
                    if (lt) { best[s] = dist; bidx[s] = code; }
                }
        }
    }

    #pragma unroll
    for (int m = 1; m < 16; m <<= 1) {
        #pragma unroll
        for (int s = 0; s < 16; ++s) {
            float ob = __shfl_xor(best[s], m);
            int   oi = __shfl_xor(bidx[s], m);
            float os = __shfl_xor(sec[s], m);
            if (ob < best[s] || (ob == best[s] && oi < bidx[s])) {
                sec[s]  = fminf(best[s], os);
                best[s] = ob; bidx[s] = oi;
            } else {
                sec[s]  = fminf(sec[s], ob);
            }
        }
    }
    __syncthreads();
    float* mg = (float*)smem;
    if (cl == 0) {
        #pragma unroll
        for (int mt = 0; mt < 4; ++mt)
            #pragma unroll
            for (int r = 0; r < 4; ++r) {
                int row = wm + mt * 16 + kq * 4 + r;
                int o = ((wn >> 6) * 128 + row) * 4;
                mg[o + 0] = best[mt * 4 + r];
                mg[o + 1] = __int_as_float(bidx[mt * 4 + r]);
                mg[o + 2] = sec[mt * 4 + r];
            }
    }
    __syncthreads();
    if (tid < MT) {
        float b0 = mg[tid * 4],         s0v = mg[tid * 4 + 2];
        int   i0 = __float_as_int(mg[tid * 4 + 1]);
        float b1 = mg[(128 + tid) * 4], s1v = mg[(128 + tid) * 4 + 2];
        int   i1 = __float_as_int(mg[(128 + tid) * 4 + 1]);
        float B, S; int I;
        if (b1 < b0 || (b1 == b0 && i1 < i0)) { B = b1; I = i1; S = fminf(s1v, b0); }
        else                                   { B = b0; I = i0; S = fminf(s0v, b1); }
        partial[(size_t)split * N_TOK + m0 + tid] = make_float4(B, __int_as_float(I), S, 0.f);
    }
}

// ---------------- kernel 4: combine splits, emit idx + flag list ----------------
__global__ __launch_bounds__(256)
void k_combine(const float4* __restrict__ partial, int* __restrict__ idxi,
               float* __restrict__ idxf, int* __restrict__ flagc,
               int* __restrict__ flag_list, int splits, float eps, int cap) {
    const int t = blockIdx.x * 256 + threadIdx.x;
    float B = 3.4e38f, S = 3.4e38f; int I = 0;
    for (int s = 0; s < splits; ++s) {
        float4 p = partial[(size_t)s * N_TOK + t];
        int oi = __float_as_int(p.y);
        if (p.x < B || (p.x == B && oi < I)) { S = fminf(B, p.z); B = p.x; I = oi; }
        else                                  { S = fminf(S, p.x); }
    }
    idxi[t] = I;
    idxf[t] = (float)I;
    if (S - B < eps) {
        int pos = atomicAdd(flagc, 1);
        if (pos < cap) flag_list[pos] = t;
    }
}

// float8 -> bf16 hi/lo staging (for stage-2 and fallback)
__device__ __forceinline__ void stage8(const float* __restrict__ gp,
                                       ushort* __restrict__ h, ushort* __restrict__ l) {
    float4 v0 = *(const float4*)gp;
    float4 v1 = *(const float4*)(gp + 4);
    uint4 hp, lp;
    PK(v0.x, v0.y, hp.x, lp.x);
    PK(v0.z, v0.w, hp.y, lp.y);
    PK(v1.x, v1.y, hp.z, lp.z);
    PK(v1.z, v1.w, hp.w, lp.w);
    *(uint4*)h = hp;
    *(uint4*)l = lp;
}

// ---------------- kernel 5: gathered bf16 3-term rescore GEMM (flagged tokens) ----------------
// grid (FLAG_CAP/64, 16): 64 flagged tokens x 512 codes per block (2 chunks x 256).
__global__ __launch_bounds__(256, 2)
void k_argmin2(const float* __restrict__ ze, const float* __restrict__ cb,
               const float* __restrict__ cnorm, const int* __restrict__ flag_list,
               const int* __restrict__ flagc, float4* __restrict__ partial2) {
    int nf = flagc[0]; if (nf > FLAG_CAP) nf = FLAG_CAP;
    const int m0 = blockIdx.x * 64;
    if (m0 >= nf) return;

    __shared__ ushort smem2[(64 + 64 + 256 + 256) * ASTR];   // Ah, Al, Bh, Bl
    ushort* Ah = smem2;
    ushort* Al = Ah + 64 * ASTR;
    ushort* Bh = Al + 64 * ASTR;
    ushort* Bl = Bh + 256 * ASTR;

    const int tid  = threadIdx.x;
    const int lane = tid & 63;
    const int wid  = tid >> 6;
    const int cl   = lane & 15;
    const int kq   = lane >> 4;
    const int wn   = wid * 64;          // 4 waves span 256 codes, same 64 rows
    const int split = blockIdx.y;       // 0..15, 512 codes each

    const int r0 = tid >> 2;            // 0..63
    const int g0 = (tid & 3) * 8;
    int tokr = m0 + r0; if (tokr > nf - 1) tokr = nf - 1;
    const int tok = flag_list[tokr];
    const float* zeA = ze + (size_t)tok * DD + g0;

    const int boff = (wn + cl) * ASTR + kq * 8;

    float best[16], sec[16]; int bidx[16];
    #pragma unroll
    for (int s = 0; s < 16; ++s) { best[s] = 3.4e38f; sec[s] = 3.4e38f; bidx[s] = 0; }

    for (int ch = 0; ch < 2; ++ch) {
        const int c0 = split * 512 + ch * 256;
        const float* cbB = cb + (size_t)(c0 + r0) * DD + g0;
        f32x4 acc[4][4];
        #pragma unroll
        for (int mt = 0; mt < 4; ++mt)
            #pragma unroll
            for (int nt = 0; nt < 4; ++nt)
                acc[mt][nt] = (f32x4){0.f, 0.f, 0.f, 0.f};

        for (int ks = 0; ks < 8; ++ks) {
            __syncthreads();
            stage8(zeA + ks * 32, Ah + r0 * ASTR + g0, Al + r0 * ASTR + g0);
            #pragma unroll
            for (int rep = 0; rep < 4; ++rep)
                stage8(cbB + (size_t)rep * 64 * DD + ks * 32,
                       Bh + (r0 + rep * 64) * ASTR + g0, Bl + (r0 + rep * 64) * ASTR + g0);
            __syncthreads();

            bf16x8 bh[4], bl[4];
            #pragma unroll
            for (int nt = 0; nt < 4; ++nt) {
                bh[nt] = *(const bf16x8*)(Bh + boff + nt * 16 * ASTR);
                bl[nt] = *(const bf16x8*)(Bl + boff + nt * 16 * ASTR);
            }
            #pragma unroll
            for (int mt = 0; mt < 4; ++mt) {
                const int ao = (mt * 16 + cl) * ASTR + kq * 8;
                bf16x8 ah = *(const bf16x8*)(Ah + ao);
                bf16x8 al = *(const bf16x8*)(Al + ao);
                #pragma unroll
                for (int nt = 0; nt < 4; ++nt) {
                    acc[mt][nt] = __builtin_amdgcn_mfma_f32_16x16x32_bf16(ah, bh[nt], acc[mt][nt], 0, 0, 0);
                    acc[mt][nt] = __builtin_amdgcn_mfma_f32_16x16x32_bf16(ah, bl[nt], acc[mt][nt], 0, 0, 0);
                    acc[mt][nt] = __builtin_amdgcn_mfma_f32_16x16x32_bf16(al, bh[nt], acc[mt][nt], 0, 0, 0);
                }
            }
        }
        #pragma unroll
        for (int nt = 0; nt < 4; ++nt) {
            const int code = c0 + wn + nt * 16 + cl;
            const float cn = cnorm[code];
            #pragma unroll
            for (int mt = 0; mt < 4; ++mt)
                #pragma unroll
                for (int r = 0; r < 4; ++r) {
                    float dist = fmaf(-2.f, acc[mt][nt][r], cn);
                    int s = mt * 4 + r;
                    bool lt = dist < best[s];
                    sec[s] = lt ? best[s] : fminf(sec[s], dist);
                    if (lt) { best[s] = dist; bidx[s] = code; }
                }
        }
    }

    #pragma unroll
    for (int m = 1; m < 16; m <<= 1) {
        #pragma unroll
        for (int s = 0; s < 16; ++s) {
            float ob = __shfl_xor(best[s], m);
            int   oi = __shfl_xor(bidx[s], m);
            float os = __shfl_xor(sec[s], m);
            if (ob < best[s] || (ob == best[s] && oi < bidx[s])) {
                sec[s]  = fminf(best[s], os);
                best[s] = ob; bidx[s] = oi;
            } else {
                sec[s]  = fminf(sec[s], ob);
            }
        }
    }
    __syncthreads();
    float* mg = (float*)smem2;                // [4 waves][64 rows][4]
    if (cl == 0) {
        #pragma unroll
        for (int mt = 0; mt < 4; ++mt)
            #pragma unroll
            for (int r = 0; r < 4; ++r) {
                int row = mt * 16 + kq * 4 + r;
                int o = (wid * 64 + row) * 4;
                mg[o + 0] = best[mt * 4 + r];
                mg[o + 1] = __int_as_float(bidx[mt * 4 + r]);
                mg[o + 2] = sec[mt * 4 + r];
            }
    }
    __syncthreads();
    if (tid < 64 && m0 + tid < nf) {
        float B = 3.4e38f, S = 3.4e38f; int I = 0;
        #pragma unroll
        for (int j = 0; j < 4; ++j) {
            float b = mg[(j * 64 + tid) * 4];
            int   i = __float_as_int(mg[(j * 64 + tid) * 4 + 1]);
            float s = mg[(j * 64 + tid) * 4 + 2];
            if (b < B || (b == B && i < I)) { S = fminf(B, s); B = b; I = i; }
            else                             { S = fminf(S, b); }
        }
        partial2[(size_t)split * FLAG_CAP + m0 + tid] = make_float4(B, __int_as_float(I), S, 0.f);
    }
}

// ---------------- kernel 6: combine stage-2 splits ----------------
__global__ __launch_bounds__(256)
void k_combine2(const float4* __restrict__ partial2, const int* __restrict__ flag_list,
                const int* __restrict__ flagc, int* __restrict__ idxi,
                float* __restrict__ idxf, int* __restrict__ flagc2,
                int* __restrict__ list2) {
    int nf = flagc[0]; if (nf > FLAG_CAP) nf = FLAG_CAP;
    const int f = blockIdx.x * 256 + threadIdx.x;
    if (f >= nf) return;
    float B = 3.4e38f, S = 3.4e38f; int I = 0;
    #pragma unroll
    for (int s = 0; s < 16; ++s) {
        float4 p = partial2[(size_t)s * FLAG_CAP + f];
        int oi = __float_as_int(p.y);
        if (p.x < B || (p.x == B && oi < I)) { S = fminf(B, p.z); B = p.x; I = oi; }
        else                                  { S = fminf(S, p.x); }
    }
    const int t = flag_list[f];
    idxi[t] = I;
    idxf[t] = (float)I;
    if (S - B < EPS2) {
        int pos = atomicAdd(flagc2, 1);
        if (pos < CAP2) list2[pos] = t;
    }
}

// ---------------- kernel 7: exact fp32 rescore ----------------
__global__ __launch_bounds__(256)
void k_rescore(const float* __restrict__ ze, const float* __restrict__ cb,
               const float* __restrict__ cnorm, const int* __restrict__ flagc,
               const int* __restrict__ flag_list, int* __restrict__ idxi,
               float* __restrict__ idxf, int cap) {
    __shared__ float xsh[DD];
    __shared__ float2 red[256];
    const int tid = threadIdx.x;
    int nf = flagc[0]; if (nf > cap) nf = cap;
    for (int f = blockIdx.x; f < nf; f += gridDim.x) {
        const int t = flag_list[f];
        if (tid < 64) *(float4*)&xsh[tid * 4] = ((const float4*)ze)[(size_t)t * D4 + tid];
        __syncthreads();
        float B = 3.4e38f; int I = 0;
        for (int c = tid; c < KC; c += 256) {
            const float4* cr = (const float4*)(cb + (size_t)c * DD);
            float dot = 0.f;
            #pragma unroll 8
            for (int j = 0; j < D4; ++j) {
                float4 cv = cr[j];
                float4 xv = *(const float4*)&xsh[j * 4];
                dot = fmaf(cv.x, xv.x, dot);
                dot = fmaf(cv.y, xv.y, dot);
                dot = fmaf(cv.z, xv.z, dot);
                dot = fmaf(cv.w, xv.w, dot);
            }
            float dist = fmaf(-2.f, dot, cnorm[c]);
            if (dist < B) { B = dist; I = c; }
        }
        red[tid] = make_float2(B, __int_as_float(I));
        __syncthreads();
        for (int s = 128; s > 0; s >>= 1) {
            if (tid < s) {
                float2 o = red[tid + s], me = red[tid];
                int oi = __float_as_int(o.y), mi = __float_as_int(me.y);
                if (o.x < me.x || (o.x == me.x && oi < mi)) red[tid] = o;
            }
            __syncthreads();
        }
        if (tid == 0) { int I2 = __float_as_int(red[0].y); idxi[t] = I2; idxf[t] = (float)I2; }
        __syncthreads();
    }
}

// ---------------- kernel 8: gather + STE output + loss partial ----------------
__global__ __launch_bounds__(256)
void k_gather(const float* __restrict__ ze, const float* __restrict__ cb,
              const int* __restrict__ idxi, float* __restrict__ zq,
              double* __restrict__ accum) {
    const int tid = threadIdx.x;
    const int t0  = blockIdx.x * 16;
    double dsum = 0.0;
    #pragma unroll
    for (int i = 0; i < 4; ++i) {
        int f = tid + i * 256;
        int row = f >> 6, e = f & 63;
        int t = t0 + row;
        int code = idxi[t];
        float4 zev = ((const float4*)ze)[(size_t)t * D4 + e];
        float4 cbv = ((const float4*)cb)[(size_t)code * D4 + e];
        float dx = cbv.x - zev.x, dy = cbv.y - zev.y;
        float dz = cbv.z - zev.z, dw = cbv.w - zev.w;
        float4 o;
        o.x = zev.x + dx; o.y = zev.y + dy; o.z = zev.z + dz; o.w = zev.w + dw;
        ((float4*)zq)[(size_t)t * D4 + e] = o;
        dsum += (double)dx * dx + (double)dy * dy + (double)dz * dz + (double)dw * dw;
    }
    #pragma unroll
    for (int off = 32; off > 0; off >>= 1) dsum += __shfl_down(dsum, off);
    __shared__ double wsum[4];
    if ((tid & 63) == 0) wsum[tid >> 6] = dsum;
    __syncthreads();
    if (tid == 0) atomicAdd(accum, wsum[0] + wsum[1] + wsum[2] + wsum[3]);
}

// ---------------- kernel 9: finalize loss ----------------
__global__ void k_final(const double* __restrict__ accum, float* __restrict__ loss) {
    loss[0] = (float)(accum[0] * (1.25 / 8388608.0));
}

// ---------------- fallback: R2-style 3-term in-loop-conversion GEMM ----------------
__global__ __launch_bounds__(256, 2)
void k_argmin_fb(const float* __restrict__ ze, const float* __restrict__ cb,
                 const float* __restrict__ cnorm, float4* __restrict__ partial) {
    __shared__ ushort smem[4 * 128 * ASTR];
    ushort* Ah = smem;
    ushort* Al = smem + 128 * ASTR;
    ushort* Bh = smem + 2 * 128 * ASTR;
    ushort* Bl = smem + 3 * 128 * ASTR;

    const int tid  = threadIdx.x;
    const int lane = tid & 63;
    const int wid  = tid >> 6;
    const int cl   = lane & 15;
    const int kq   = lane >> 4;
    const int wm   = (wid & 1) * 64;
    const int wn   = (wid >> 1) * 64;
    const int m0   = blockIdx.x * MT;
    const int split = blockIdx.y;

    const int r0 = tid >> 2;
    const int g0 = (tid & 3) * 8;
    const float* zeA = ze + (size_t)(m0 + r0) * DD + g0;
    const int aoff = (wm + cl) * ASTR + kq * 8;
    const int boff = (wn + cl) * ASTR + kq * 8;

    float best[16], sec[16]; int bidx[16];
    #pragma unroll
    for (int s = 0; s < 16; ++s) { best[s] = 3.4e38f; sec[s] = 3.4e38f; bidx[s] = 0; }

    for (int ch = 0; ch < 4; ++ch) {
        const int c0 = split * 512 + ch * NT;
        const float* cbB = cb + (size_t)(c0 + r0) * DD + g0;
        f32x4 acc[4][4];
        #pragma unroll
        for (int mt = 0; mt < 4; ++mt)
            #pragma unroll
            for (int nt = 0; nt < 4; ++nt)
                acc[mt][nt] = (f32x4){0.f, 0.f, 0.f, 0.f};

        for (int ks = 0; ks < 8; ++ks) {
            __syncthreads();
            stage8(zeA + ks * 32,            Ah + r0 * ASTR + g0, Al + r0 * ASTR + g0);
            stage8(zeA + 64 * DD + ks * 32,  Ah + (r0 + 64) * ASTR + g0, Al + (r0 + 64) * ASTR + g0);
            stage8(cbB + ks * 32,            Bh + r0 * ASTR + g0, Bl + r0 * ASTR + g0);
            stage8(cbB + 64 * DD + ks * 32,  Bh + (r0 + 64) * ASTR + g0, Bl + (r0 + 64) * ASTR + g0);
            __syncthreads();

            bf16x8 bh[4], bl[4];
            #pragma unroll
            for (int nt = 0; nt < 4; ++nt) {
                bh[nt] = *(const bf16x8*)(Bh + boff + nt * 16 * ASTR);
                bl[nt] = *(const bf16x8*)(Bl + boff + nt * 16 * ASTR);
            }
            #pragma unroll
            for (int mt = 0; mt < 4; ++mt) {
                bf16x8 ah = *(const bf16x8*)(Ah + aoff + mt * 16 * ASTR);
                bf16x8 al = *(const bf16x8*)(Al + aoff + mt * 16 * ASTR);
                #pragma unroll
                for (int nt = 0; nt < 4; ++nt) {
                    acc[mt][nt] = __builtin_amdgcn_mfma_f32_16x16x32_bf16(ah, bh[nt], acc[mt][nt], 0, 0, 0);
                    acc[mt][nt] = __builtin_amdgcn_mfma_f32_16x16x32_bf16(ah, bl[nt], acc[mt][nt], 0, 0, 0);
                    acc[mt][nt] = __builtin_amdgcn_mfma_f32_16x16x32_bf16(al, bh[nt], acc[mt][nt], 0, 0, 0);
                }
            }
        }
        #pragma unroll
        for (int nt = 0; nt < 4; ++nt) {
            const int code = c0 + wn + nt * 16 + cl;
            const float cn = cnorm[code];
            #pragma unroll
            for (int mt = 0; mt < 4; ++mt)
                #pragma unroll
                for (int r = 0; r < 4; ++r) {
                    float dist = fmaf(-2.f, acc[mt][nt][r], cn);
                    int s = mt * 4 + r;
                    bool lt = dist < best[s];
                    sec[s] = lt ? best[s] : fminf(sec[s], dist);
                    if (lt) { best[s] = dist; bidx[s] = code; }
                }
        }
    }

    #pragma unroll
    for (int m = 1; m < 16; m <<= 1) {
        #pragma unroll
        for (int s = 0; s < 16; ++s) {
            float ob = __shfl_xor(best[s], m);
            int   oi = __shfl_xor(bidx[s], m);
            float os = __shfl_xor(sec[s], m);
            if (ob < best[s] || (ob == best[s] && oi < bidx[s])) {
                sec[s]  = fminf(best[s], os);
                best[s] = ob; bidx[s] = oi;
            } else {
                sec[s]  = fminf(sec[s], ob);
            }
        }
    }
    __syncthreads();
    float* mg = (float*)smem;
    if (cl == 0) {
        #pragma unroll
        for (int mt = 0; mt < 4; ++mt)
            #pragma unroll
            for (int r = 0; r < 4; ++r) {
                int row = wm + mt * 16 + kq * 4 + r;
                int o = ((wn >> 6) * 128 + row) * 4;
                mg[o + 0] = best[mt * 4 + r];
                mg[o + 1] = __int_as_float(bidx[mt * 4 + r]);
                mg[o + 2] = sec[mt * 4 + r];
            }
    }
    __syncthreads();
    if (tid < MT) {
        float b0 = mg[tid * 4],         s0v = mg[tid * 4 + 2];
        int   i0 = __float_as_int(mg[tid * 4 + 1]);
        float b1 = mg[(128 + tid) * 4], s1v = mg[(128 + tid) * 4 + 2];
        int   i1 = __float_as_int(mg[(128 + tid) * 4 + 1]);
        float B, S; int I;
        if (b1 < b0 || (b1 == b0 && i1 < i0)) { B = b1; I = i1; S = fminf(s1v, b0); }
        else                                   { B = b0; I = i0; S = fminf(s0v, b1); }
        partial[(size_t)split * N_TOK + m0 + tid] = make_float4(B, __int_as_float(I), S, 0.f);
    }
}

extern "C" void kernel_launch(void* const* d_in, const int* in_sizes, int n_in,
                              void* d_out, int out_size, void* d_ws, size_t ws_size,
                              hipStream_t stream) {
    const float* ze = (const float*)d_in[0];
    const float* cb = (const float*)d_in[1];

    float* out      = (float*)d_out;
    float* out_zq   = out;
    float* out_idx  = out + (size_t)N_TOK * DD;
    float* out_loss = out_idx + N_TOK;

    char*   ws    = (char*)d_ws;
    float*  cnorm = (float*)ws;                     // 32 KB
    int*    idxi  = (int*)(ws + 32768);             // 128 KB
    double* accum = (double*)(ws + 163840);
    int*    flagc = (int*)(ws + 163848);
    int*    flagc2= (int*)(ws + 163852);
    int*    flag_list = (int*)(ws + 163856);        // 32 KB
    int*    list2     = (int*)(ws + 196624);        // 16 KB

    const size_t OFF_ZEF  = 213008;                               // 16.78 MB
    const size_t OFF_CBF  = OFF_ZEF + (size_t)N_TOK * DD * 2;     // 4.19 MB
    const size_t OFF_P1   = OFF_CBF + (size_t)KC * DD * 2;        // 4.19 MB
    const size_t OFF_P2   = OFF_P1 + (size_t)SPLITS * N_TOK * 16; // 2.10 MB
    const size_t NEED     = OFF_P2 + 16ull * FLAG_CAP * 16;       // ~27.5 MB

    if (ws_size >= NEED) {
        _Float16* zef = (_Float16*)(ws + OFF_ZEF);
        _Float16* cbf = (_Float16*)(ws + OFF_CBF);
        float4* partial  = (float4*)(ws + OFF_P1);
        float4* partial2 = (float4*)(ws + OFF_P2);

        hipLaunchKernelGGL(k_cnorm, dim3(KC / 4), dim3(256), 0, stream,
                           cb, cnorm, accum, flagc, flagc2, cbf);
        hipLaunchKernelGGL(k_convert_ze, dim3(N_TOK * DD / 8 / 256), dim3(256), 0, stream,
                           ze, zef, N_TOK * DD / 8);
        hipLaunchKernelGGL(k_argmin_f16, dim3(N_TOK / MT, SPLITS), dim3(256), 0, stream,
                           zef, cbf, cnorm, partial);
        hipLaunchKernelGGL(k_combine, dim3(N_TOK / 256), dim3(256), 0, stream,
                           partial, idxi, out_idx, flagc, flag_list, SPLITS, EPS1, FLAG_CAP);
        hipLaunchKernelGGL(k_argmin2, dim3(FLAG_CAP / 64, 16), dim3(256), 0, stream,
                           ze, cb, cnorm, flag_list, flagc, partial2);
        hipLaunchKernelGGL(k_combine2, dim3(FLAG_CAP / 256), dim3(256), 0, stream,
                           partial2, flag_list, flagc, idxi, out_idx, flagc2, list2);
        hipLaunchKernelGGL(k_rescore, dim3(128), dim3(256), 0, stream,
                           ze, cb, cnorm, flagc2, list2, idxi, out_idx, CAP2);
    } else {
        // fallback: R2-style full 3-term GEMM, 16 splits, partial in d_out
        hipLaunchKernelGGL(k_cnorm, dim3(KC / 4), dim3(256), 0, stream,
                           cb, cnorm, accum, flagc, flagc2, (_Float16*)0);
        float4* partial = (float4*)d_out;
        int* fl = (int*)(ws + 163856);
        hipLaunchKernelGGL(k_argmin_fb, dim3(N_TOK / MT, 16), dim3(256), 0, stream,
                           ze, cb, cnorm, partial);
        hipLaunchKernelGGL(k_combine, dim3(N_TOK / 256), dim3(256), 0, stream,
                           partial, idxi, out_idx, flagc, fl, 16, EPS2, FLAG_CAP);
        hipLaunchKernelGGL(k_rescore, dim3(128), dim3(256), 0, stream,
                           ze, cb, cnorm, flagc, fl, idxi, out_idx, FLAG_CAP);
    }

    hipLaunchKernelGGL(k_gather, dim3(N_TOK / 16), dim3(256), 0, stream, ze, cb, idxi, out_zq, accum);
    hipLaunchKernelGGL(k_final,  dim3(1), dim3(1), 0, stream, accum, out_loss);
}

// Round 5
// 580.761 us; speedup vs baseline: 2.1182x; 2.1182x over previous
//
#include <hip/hip_runtime.h>

// VectorQuantizer: N=32768 tokens, K=8192 codes, D=256, fp32 in/out.
// Outputs (concat, float): z_q_ste[32768*256], idx[32768] (as float), loss[1].
// R5: stage-1 fp16 GEMM restructured: A (128 tokens, full K) in registers,
// B streamed through LDS double-buffer with prefetch issued one iteration
// ahead (near-free barrier drain). Each block reads each input byte once.
// Cascade: gap<0.025 -> bf16 3-term rescore over all codes; gap<1e-3 -> fp32.

#define N_TOK   32768
#define KC      8192
#define DD      256
#define D4      64
#define CSPL    2               // code splits for stage-1
#define MT      128
#define EPS1    0.025f
#define EPS2    1e-3f
#define FLAG_CAP 8192
#define CAP2     4096
#define ASTR    40

typedef __bf16    bf16x8 __attribute__((ext_vector_type(8)));
typedef _Float16  f16x8  __attribute__((ext_vector_type(8)));
typedef _Float16  f16x4  __attribute__((ext_vector_type(4)));
typedef float     f32x4  __attribute__((ext_vector_type(4)));

#define GLL(gp, lp) __builtin_amdgcn_global_load_lds(                                   \
    (const __attribute__((address_space(1))) void*)(unsigned long long)(uintptr_t)(gp), \
    (__attribute__((address_space(3))) void*)(unsigned)(uintptr_t)(lp), 16, 0, 0)

#define PK(a, b, HO, LO) do {                                   \
    unsigned ua = __float_as_uint(a), ub = __float_as_uint(b);  \
    unsigned ham = ua & 0xFFFF0000u, hbm = ub & 0xFFFF0000u;    \
    float la = (a) - __uint_as_float(ham);                      \
    float lb = (b) - __uint_as_float(hbm);                      \
    HO = (ua >> 16) | hbm;                                      \
    LO = (__float_as_uint(la) >> 16) | (__float_as_uint(lb) & 0xFFFF0000u); \
} while (0)

// ---------------- kernel 1: code norms + cb->f16 + zero accumulators ----------------
__global__ __launch_bounds__(256)
void k_cnorm(const float* __restrict__ cb, float* __restrict__ cnorm,
             double* __restrict__ accum, int* __restrict__ flagc,
             int* __restrict__ flagc2, _Float16* __restrict__ cbf16) {
    if (blockIdx.x == 0 && threadIdx.x == 0) { *accum = 0.0; *flagc = 0; *flagc2 = 0; }
    const int gid  = blockIdx.x * 256 + threadIdx.x;
    const int code = gid >> 6;
    const int lane = threadIdx.x & 63;
    if (code < KC) {
        float4 v = ((const float4*)cb)[code * D4 + lane];
        if (cbf16) {
            f16x4 h;
            h[0] = (_Float16)v.x; h[1] = (_Float16)v.y;
            h[2] = (_Float16)v.z; h[3] = (_Float16)v.w;
            *(f16x4*)(cbf16 + (size_t)code * DD + lane * 4) = h;
        }
        float s = v.x*v.x + v.y*v.y + v.z*v.z + v.w*v.w;
        #pragma unroll
        for (int off = 32; off > 0; off >>= 1) s += __shfl_down(s, off);
        if (lane == 0) cnorm[code] = s;
    }
}

// ---------------- kernel 2: z_e -> fp16 ----------------
__global__ __launch_bounds__(256)
void k_convert_ze(const float* __restrict__ src, _Float16* __restrict__ dst, int n8) {
    int t = blockIdx.x * 256 + threadIdx.x;
    if (t >= n8) return;
    const float4* s = (const float4*)src;
    float4 v0 = s[2 * t], v1 = s[2 * t + 1];
    f16x8 h;
    h[0] = (_Float16)v0.x; h[1] = (_Float16)v0.y; h[2] = (_Float16)v0.z; h[3] = (_Float16)v0.w;
    h[4] = (_Float16)v1.x; h[5] = (_Float16)v1.y; h[6] = (_Float16)v1.z; h[7] = (_Float16)v1.w;
    ((f16x8*)dst)[t] = h;
}

// ---------------- kernel 3: stage-1 fp16 GEMM, A-in-regs + B dbuf stream ----------------
__global__ __launch_bounds__(256)
void k_argmin_f16(const _Float16* __restrict__ zef, const _Float16* __restrict__ cbf,
                  const float* __restrict__ cnorm, float4* __restrict__ partial) {
    // LDS: phase 1: A tile 128 rows x 512 B (64 KB). phase 2: B dbuf 2 x 32 KB.
    // XOR swizzle: 16B chunk (row, c) stored at row*512 + ((c ^ (row&31))<<4).
    __shared__ __align__(16) char smem[65536];

    const int tid  = threadIdx.x;
    const int lane = tid & 63;
    const int wid  = tid >> 6;
    const int cl   = lane & 15;
    const int kq   = lane >> 4;
    const int m0   = blockIdx.x * MT;
    const int split = blockIdx.y;
    const int c0b  = split * (KC / CSPL);      // 4096 codes per split
    const int wrow0 = wid * 32;                // wave's 32 token rows

    // ---- phase 1: stage full-K A tile once, pull fragments into registers ----
    {
        const int lr = lane >> 5;              // 0..1 row within 1KB GLL
        const int lc = lane & 31;              // swizzled chunk
        #pragma unroll
        for (int j = 0; j < 16; ++j) {
            int I = wid * 16 + j;              // 0..63 -> rows 2I, 2I+1
            int r = 2 * I + lr;
            int c = lc ^ (r & 31);
            GLL((const char*)zef + (size_t)(m0 + r) * 512 + c * 16, smem + I * 1024);
        }
    }
    __syncthreads();
    f16x8 afr[2][8];
    #pragma unroll
    for (int mt = 0; mt < 2; ++mt)
        #pragma unroll
        for (int ks = 0; ks < 8; ++ks) {
            int row = wrow0 + mt * 16 + cl;
            int c   = ks * 4 + kq;
            afr[mt][ks] = *(const f16x8*)(smem + row * 512 + (((c ^ (row & 31))) << 4));
        }
    __syncthreads();                           // A LDS free -> becomes B dbuf

    // ---- phase 2: stream B (64 codes x full K per ch), dbuf + early prefetch ----
    char* bbuf0 = smem;
    char* bbuf1 = smem + 32768;
    const int lr = lane >> 5;
    const int lc = lane & 31;

    // stage ch=0 into bbuf0
    #pragma unroll
    for (int j = 0; j < 8; ++j) {
        int I = wid * 8 + j;                   // 0..31 -> rows 2I, 2I+1 (codes)
        int r = 2 * I + lr;
        int c = lc ^ (r & 31);
        GLL((const char*)cbf + (size_t)(c0b + r) * 512 + c * 16, bbuf0 + I * 1024);
    }
    __syncthreads();

    float best[8], sec[8]; int bidx[8];
    #pragma unroll
    for (int s = 0; s < 8; ++s) { best[s] = 3.4e38f; sec[s] = 3.4e38f; bidx[s] = 0; }

    for (int ch = 0; ch < 64; ++ch) {
        char* cur = (ch & 1) ? bbuf1 : bbuf0;
        char* nxt = (ch & 1) ? bbuf0 : bbuf1;
        if (ch < 63) {                         // prefetch ch+1 a full iteration early
            const int cr0 = c0b + (ch + 1) * 64;
            #pragma unroll
            for (int j = 0; j < 8; ++j) {
                int I = wid * 8 + j;
                int r = 2 * I + lr;
                int c = lc ^ (r & 31);
                GLL((const char*)cbf + (size_t)(cr0 + r) * 512 + c * 16, nxt + I * 1024);
            }
        }

        f32x4 acc[2][4];
        #pragma unroll
        for (int mt = 0; mt < 2; ++mt)
            #pragma unroll
            for (int nt = 0; nt < 4; ++nt)
                acc[mt][nt] = (f32x4){0.f, 0.f, 0.f, 0.f};

        #pragma unroll
        for (int ks = 0; ks < 8; ++ks) {
            f16x8 bfr[4];
            #pragma unroll
            for (int nt = 0; nt < 4; ++nt) {
                int row = nt * 16 + cl;
                int c   = ks * 4 + kq;
                bfr[nt] = *(const f16x8*)(cur + row * 512 + ((c ^ (row & 31)) << 4));
            }
            #pragma unroll
            for (int mt = 0; mt < 2; ++mt)
                #pragma unroll
                for (int nt = 0; nt < 4; ++nt)
                    acc[mt][nt] = __builtin_amdgcn_mfma_f32_16x16x32_f16(afr[mt][ks], bfr[nt], acc[mt][nt], 0, 0, 0);
        }

        // fold into running top-2 (codes ascend across ch and nt: '<' keeps first idx)
        const int cc0 = c0b + ch * 64;
        #pragma unroll
        for (int nt = 0; nt < 4; ++nt) {
            const int code = cc0 + nt * 16 + cl;
            const float cn = cnorm[code];
            #pragma unroll
            for (int mt = 0; mt < 2; ++mt)
                #pragma unroll
                for (int r = 0; r < 4; ++r) {
                    float dist = fmaf(-2.f, acc[mt][nt][r], cn);
                    int s = mt * 4 + r;
                    bool lt = dist < best[s];
                    sec[s] = lt ? best[s] : fminf(sec[s], dist);
                    if (lt) { best[s] = dist; bidx[s] = code; }
                }
        }
        __syncthreads();                       // drains prefetch (issued ~600cyc ago) + buf reuse
    }

    // reduce over the 16 col-lanes (cl); masks < 16 stay within kq group
    #pragma unroll
    for (int m = 1; m < 16; m <<= 1) {
        #pragma unroll
        for (int s = 0; s < 8; ++s) {
            float ob = __shfl_xor(best[s], m);
            int   oi = __shfl_xor(bidx[s], m);
            float os = __shfl_xor(sec[s], m);
            if (ob < best[s] || (ob == best[s] && oi < bidx[s])) {
                sec[s]  = fminf(best[s], os);
                best[s] = ob; bidx[s] = oi;
            } else {
                sec[s]  = fminf(sec[s], ob);
            }
        }
    }
    if (cl == 0) {                             // lanes kq*16: own rows wrow0+mt*16+kq*4+r
        #pragma unroll
        for (int mt = 0; mt < 2; ++mt)
            #pragma unroll
            for (int r = 0; r < 4; ++r) {
                int row = wrow0 + mt * 16 + kq * 4 + r;
                int s = mt * 4 + r;
                partial[(size_t)split * N_TOK + m0 + row] =
                    make_float4(best[s], __int_as_float(bidx[s]), sec[s], 0.f);
            }
    }
}

// ---------------- kernel 4: combine splits, emit idx + flag list ----------------
__global__ __launch_bounds__(256)
void k_combine(const float4* __restrict__ partial, int* __restrict__ idxi,
               float* __restrict__ idxf, int* __restrict__ flagc,
               int* __restrict__ flag_list, int splits, float eps, int cap) {
    const int t = blockIdx.x * 256 + threadIdx.x;
    float B = 3.4e38f, S = 3.4e38f; int I = 0;
    for (int s = 0; s < splits; ++s) {
        float4 p = partial[(size_t)s * N_TOK + t];
        int oi = __float_as_int(p.y);
        if (p.x < B || (p.x == B && oi < I)) { S = fminf(B, p.z); B = p.x; I = oi; }
        else                                  { S = fminf(S, p.x); }
    }
    idxi[t] = I;
    idxf[t] = (float)I;
    if (S - B < eps) {
        int pos = atomicAdd(flagc, 1);
        if (pos < cap) flag_list[pos] = t;
    }
}

// float8 -> bf16 hi/lo staging (for stage-2 and fallback)
__device__ __forceinline__ void stage8(const float* __restrict__ gp,
                                       ushort* __restrict__ h, ushort* __restrict__ l) {
    float4 v0 = *(const float4*)gp;
    float4 v1 = *(const float4*)(gp + 4);
    uint4 hp, lp;
    PK(v0.x, v0.y, hp.x, lp.x);
    PK(v0.z, v0.w, hp.y, lp.y);
    PK(v1.x, v1.y, hp.z, lp.z);
    PK(v1.z, v1.w, hp.w, lp.w);
    *(uint4*)h = hp;
    *(uint4*)l = lp;
}

// ---------------- kernel 5: gathered bf16 3-term rescore GEMM (flagged tokens) ----------------
__global__ __launch_bounds__(256, 2)
void k_argmin2(const float* __restrict__ ze, const float* __restrict__ cb,
               const float* __restrict__ cnorm, const int* __restrict__ flag_list,
               const int* __restrict__ flagc, float4* __restrict__ partial2) {
    int nf = flagc[0]; if (nf > FLAG_CAP) nf = FLAG_CAP;
    const int m0 = blockIdx.x * 64;
    if (m0 >= nf) return;

    __shared__ ushort smem2[(64 + 64 + 256 + 256) * ASTR];
    ushort* Ah = smem2;
    ushort* Al = Ah + 64 * ASTR;
    ushort* Bh = Al + 64 * ASTR;
    ushort* Bl = Bh + 256 * ASTR;

    const int tid  = threadIdx.x;
    const int lane = tid & 63;
    const int wid  = tid >> 6;
    const int cl   = lane & 15;
    const int kq   = lane >> 4;
    const int wn   = wid * 64;
    const int split = blockIdx.y;

    const int r0 = tid >> 2;
    const int g0 = (tid & 3) * 8;
    int tokr = m0 + r0; if (tokr > nf - 1) tokr = nf - 1;
    const int tok = flag_list[tokr];
    const float* zeA = ze + (size_t)tok * DD + g0;

    const int boff = (wn + cl) * ASTR + kq * 8;

    float best[16], sec[16]; int bidx[16];
    #pragma unroll
    for (int s = 0; s < 16; ++s) { best[s] = 3.4e38f; sec[s] = 3.4e38f; bidx[s] = 0; }

    for (int ch = 0; ch < 2; ++ch) {
        const int c0 = split * 512 + ch * 256;
        const float* cbB = cb + (size_t)(c0 + r0) * DD + g0;
        f32x4 acc[4][4];
        #pragma unroll
        for (int mt = 0; mt < 4; ++mt)
            #pragma unroll
            for (int nt = 0; nt < 4; ++nt)
                acc[mt][nt] = (f32x4){0.f, 0.f, 0.f, 0.f};

        for (int ks = 0; ks < 8; ++ks) {
            __syncthreads();
            stage8(zeA + ks * 32, Ah + r0 * ASTR + g0, Al + r0 * ASTR + g0);
            #pragma unroll
            for (int rep = 0; rep < 4; ++rep)
                stage8(cbB + (size_t)rep * 64 * DD + ks * 32,
                       Bh + (r0 + rep * 64) * ASTR + g0, Bl + (r0 + rep * 64) * ASTR + g0);
            __syncthreads();

            bf16x8 bh[4], bl[4];
            #pragma unroll
            for (int nt = 0; nt < 4; ++nt) {
                bh[nt] = *(const bf16x8*)(Bh + boff + nt * 16 * ASTR);
                bl[nt] = *(const bf16x8*)(Bl + boff + nt * 16 * ASTR);
            }
            #pragma unroll
            for (int mt = 0; mt < 4; ++mt) {
                const int ao = (mt * 16 + cl) * ASTR + kq * 8;
                bf16x8 ah = *(const bf16x8*)(Ah + ao);
                bf16x8 al = *(const bf16x8*)(Al + ao);
                #pragma unroll
                for (int nt = 0; nt < 4; ++nt) {
                    acc[mt][nt] = __builtin_amdgcn_mfma_f32_16x16x32_bf16(ah, bh[nt], acc[mt][nt], 0, 0, 0);
                    acc[mt][nt] = __builtin_amdgcn_mfma_f32_16x16x32_bf16(ah, bl[nt], acc[mt][nt], 0, 0, 0);
                    acc[mt][nt] = __builtin_amdgcn_mfma_f32_16x16x32_bf16(al, bh[nt], acc[mt][nt], 0, 0, 0);
                }
            }
        }
        #pragma unroll
        for (int nt = 0; nt < 4; ++nt) {
            const int code = c0 + wn + nt * 16 + cl;
            const float cn = cnorm[code];
            #pragma unroll
            for (int mt = 0; mt < 4; ++mt)
                #pragma unroll
                for (int r = 0; r < 4; ++r) {
                    float dist = fmaf(-2.f, acc[mt][nt][r], cn);
                    int s = mt * 4 + r;
                    bool lt = dist < best[s];
                    sec[s] = lt ? best[s] : fminf(sec[s], dist);
                    if (lt) { best[s] = dist; bidx[s] = code; }
                }
        }
    }

    #pragma unroll
    for (int m = 1; m < 16; m <<= 1) {
        #pragma unroll
        for (int s = 0; s < 16; ++s) {
            float ob = __shfl_xor(best[s], m);
            int   oi = __shfl_xor(bidx[s], m);
            float os = __shfl_xor(sec[s], m);
            if (ob < best[s] || (ob == best[s] && oi < bidx[s])) {
                sec[s]  = fminf(best[s], os);
                best[s] = ob; bidx[s] = oi;
            } else {
                sec[s]  = fminf(sec[s], ob);
            }
        }
    }
    __syncthreads();
    float* mg = (float*)smem2;
    if (cl == 0) {
        #pragma unroll
        for (int mt = 0; mt < 4; ++mt)
            #pragma unroll
            for (int r = 0; r < 4; ++r) {
                int row = mt * 16 + kq * 4 + r;
                int o = (wid * 64 + row) * 4;
                mg[o + 0] = best[mt * 4 + r];
                mg[o + 1] = __int_as_float(bidx[mt * 4 + r]);
                mg[o + 2] = sec[mt * 4 + r];
            }
    }
    __syncthreads();
    if (tid < 64 && m0 + tid < nf) {
        float B = 3.4e38f, S = 3.4e38f; int I = 0;
        #pragma unroll
        for (int j = 0; j < 4; ++j) {
            float b = mg[(j * 64 + tid) * 4];
            int   i = __float_as_int(mg[(j * 64 + tid) * 4 + 1]);
            float s = mg[(j * 64 + tid) * 4 + 2];
            if (b < B || (b == B && i < I)) { S = fminf(B, s); B = b; I = i; }
            else                             { S = fminf(S, b); }
        }
        partial2[(size_t)split * FLAG_CAP + m0 + tid] = make_float4(B, __int_as_float(I), S, 0.f);
    }
}

// ---------------- kernel 6: combine stage-2 splits ----------------
__global__ __launch_bounds__(256)
void k_combine2(const float4* __restrict__ partial2, const int* __restrict__ flag_list,
                const int* __restrict__ flagc, int* __restrict__ idxi,
                float* __restrict__ idxf, int* __restrict__ flagc2,
                int* __restrict__ list2) {
    int nf = flagc[0]; if (nf > FLAG_CAP) nf = FLAG_CAP;
    const int f = blockIdx.x * 256 + threadIdx.x;
    if (f >= nf) return;
    float B = 3.4e38f, S = 3.4e38f; int I = 0;
    #pragma unroll
    for (int s = 0; s < 16; ++s) {
        float4 p = partial2[(size_t)s * FLAG_CAP + f];
        int oi = __float_as_int(p.y);
        if (p.x < B || (p.x == B && oi < I)) { S = fminf(B, p.z); B = p.x; I = oi; }
        else                                  { S = fminf(S, p.x); }
    }
    const int t = flag_list[f];
    idxi[t] = I;
    idxf[t] = (float)I;
    if (S - B < EPS2) {
        int pos = atomicAdd(flagc2, 1);
        if (pos < CAP2) list2[pos] = t;
    }
}

// ---------------- kernel 7: exact fp32 rescore ----------------
__global__ __launch_bounds__(256)
void k_rescore(const float* __restrict__ ze, const float* __restrict__ cb,
               const float* __restrict__ cnorm, const int* __restrict__ flagc,
               const int* __restrict__ flag_list, int* __restrict__ idxi,
               float* __restrict__ idxf, int cap) {
    __shared__ float xsh[DD];
    __shared__ float2 red[256];
    const int tid = threadIdx.x;
    int nf = flagc[0]; if (nf > cap) nf = cap;
    for (int f = blockIdx.x; f < nf; f += gridDim.x) {
        const int t = flag_list[f];
        if (tid < 64) *(float4*)&xsh[tid * 4] = ((const float4*)ze)[(size_t)t * D4 + tid];
        __syncthreads();
        float B = 3.4e38f; int I = 0;
        for (int c = tid; c < KC; c += 256) {
            const float4* cr = (const float4*)(cb + (size_t)c * DD);
            float dot = 0.f;
            #pragma unroll 8
            for (int j = 0; j < D4; ++j) {
                float4 cv = cr[j];
                float4 xv = *(const float4*)&xsh[j * 4];
                dot = fmaf(cv.x, xv.x, dot);
                dot = fmaf(cv.y, xv.y, dot);
                dot = fmaf(cv.z, xv.z, dot);
                dot = fmaf(cv.w, xv.w, dot);
            }
            float dist = fmaf(-2.f, dot, cnorm[c]);
            if (dist < B) { B = dist; I = c; }
        }
        red[tid] = make_float2(B, __int_as_float(I));
        __syncthreads();
        for (int s = 128; s > 0; s >>= 1) {
            if (tid < s) {
                float2 o = red[tid + s], me = red[tid];
                int oi = __float_as_int(o.y), mi = __float_as_int(me.y);
                if (o.x < me.x || (o.x == me.x && oi < mi)) red[tid] = o;
            }
            __syncthreads();
        }
        if (tid == 0) { int I2 = __float_as_int(red[0].y); idxi[t] = I2; idxf[t] = (float)I2; }
        __syncthreads();
    }
}

// ---------------- kernel 8: gather + STE output + loss partial ----------------
__global__ __launch_bounds__(256)
void k_gather(const float* __restrict__ ze, const float* __restrict__ cb,
              const int* __restrict__ idxi, float* __restrict__ zq,
              double* __restrict__ accum) {
    const int tid = threadIdx.x;
    const int t0  = blockIdx.x * 16;
    double dsum = 0.0;
    #pragma unroll
    for (int i = 0; i < 4; ++i) {
        int f = tid + i * 256;
        int row = f >> 6, e = f & 63;
        int t = t0 + row;
        int code = idxi[t];
        float4 zev = ((const float4*)ze)[(size_t)t * D4 + e];
        float4 cbv = ((const float4*)cb)[(size_t)code * D4 + e];
        float dx = cbv.x - zev.x, dy = cbv.y - zev.y;
        float dz = cbv.z - zev.z, dw = cbv.w - zev.w;
        float4 o;
        o.x = zev.x + dx; o.y = zev.y + dy; o.z = zev.z + dz; o.w = zev.w + dw;
        ((float4*)zq)[(size_t)t * D4 + e] = o;
        dsum += (double)dx * dx + (double)dy * dy + (double)dz * dz + (double)dw * dw;
    }
    #pragma unroll
    for (int off = 32; off > 0; off >>= 1) dsum += __shfl_down(dsum, off);
    __shared__ double wsum[4];
    if ((tid & 63) == 0) wsum[tid >> 6] = dsum;
    __syncthreads();
    if (tid == 0) atomicAdd(accum, wsum[0] + wsum[1] + wsum[2] + wsum[3]);
}

// ---------------- kernel 9: finalize loss ----------------
__global__ void k_final(const double* __restrict__ accum, float* __restrict__ loss) {
    loss[0] = (float)(accum[0] * (1.25 / 8388608.0));
}

// ---------------- fallback: R2-style 3-term in-loop-conversion GEMM ----------------
__global__ __launch_bounds__(256, 2)
void k_argmin_fb(const float* __restrict__ ze, const float* __restrict__ cb,
                 const float* __restrict__ cnorm, float4* __restrict__ partial) {
    __shared__ ushort smem[4 * 128 * ASTR];
    ushort* Ah = smem;
    ushort* Al = smem + 128 * ASTR;
    ushort* Bh = smem + 2 * 128 * ASTR;
    ushort* Bl = smem + 3 * 128 * ASTR;

    const int tid  = threadIdx.x;
    const int lane = tid & 63;
    const int wid  = tid >> 6;
    const int cl   = lane & 15;
    const int kq   = lane >> 4;
    const int wm   = (wid & 1) * 64;
    const int wn   = (wid >> 1) * 64;
    const int m0   = blockIdx.x * MT;
    const int split = blockIdx.y;

    const int r0 = tid >> 2;
    const int g0 = (tid & 3) * 8;
    const float* zeA = ze + (size_t)(m0 + r0) * DD + g0;
    const int aoff = (wm + cl) * ASTR + kq * 8;
    const int boff = (wn + cl) * ASTR + kq * 8;

    float best[16], sec[16]; int bidx[16];
    #pragma unroll
    for (int s = 0; s < 16; ++s) { best[s] = 3.4e38f; sec[s] = 3.4e38f; bidx[s] = 0; }

    for (int ch = 0; ch < 4; ++ch) {
        const int c0 = split * 512 + ch * 128;
        const float* cbB = cb + (size_t)(c0 + r0) * DD + g0;
        f32x4 acc[4][4];
        #pragma unroll
        for (int mt = 0; mt < 4; ++mt)
            #pragma unroll
            for (int nt = 0; nt < 4; ++nt)
                acc[mt][nt] = (f32x4){0.f, 0.f, 0.f, 0.f};

        for (int ks = 0; ks < 8; ++ks) {
            __syncthreads();
            stage8(zeA + ks * 32,            Ah + r0 * ASTR + g0, Al + r0 * ASTR + g0);
            stage8(zeA + 64 * DD + ks * 32,  Ah + (r0 + 64) * ASTR + g0, Al + (r0 + 64) * ASTR + g0);
            stage8(cbB + ks * 32,            Bh + r0 * ASTR + g0, Bl + r0 * ASTR + g0);
            stage8(cbB + 64 * DD + ks * 32,  Bh + (r0 + 64) * ASTR + g0, Bl + (r0 + 64) * ASTR + g0);
            __syncthreads();

            bf16x8 bh[4], bl[4];
            #pragma unroll
            for (int nt = 0; nt < 4; ++nt) {
                bh[nt] = *(const bf16x8*)(Bh + boff + nt * 16 * ASTR);
                bl[nt] = *(const bf16x8*)(Bl + boff + nt * 16 * ASTR);
            }
            #pragma unroll
            for (int mt = 0; mt < 4; ++mt) {
                bf16x8 ah = *(const bf16x8*)(Ah + aoff + mt * 16 * ASTR);
                bf16x8 al = *(const bf16x8*)(Al + aoff + mt * 16 * ASTR);
                #pragma unroll
                for (int nt = 0; nt < 4; ++nt) {
                    acc[mt][nt] = __builtin_amdgcn_mfma_f32_16x16x32_bf16(ah, bh[nt], acc[mt][nt], 0, 0, 0);
                    acc[mt][nt] = __builtin_amdgcn_mfma_f32_16x16x32_bf16(ah, bl[nt], acc[mt][nt], 0, 0, 0);
                    acc[mt][nt] = __builtin_amdgcn_mfma_f32_16x16x32_bf16(al, bh[nt], acc[mt][nt], 0, 0, 0);
                }
            }
        }
        #pragma unroll
        for (int nt = 0; nt < 4; ++nt) {
            const int code = c0 + wn + nt * 16 + cl;
            const float cn = cnorm[code];
            #pragma unroll
            for (int mt = 0; mt < 4; ++mt)
                #pragma unroll
                for (int r = 0; r < 4; ++r) {
                    float dist = fmaf(-2.f, acc[mt][nt][r], cn);
                    int s = mt * 4 + r;
                    bool lt = dist < best[s];
                    sec[s] = lt ? best[s] : fminf(sec[s], dist);
                    if (lt) { best[s] = dist; bidx[s] = code; }
                }
        }
    }

    #pragma unroll
    for (int m = 1; m < 16; m <<= 1) {
        #pragma unroll
        for (int s = 0; s < 16; ++s) {
            float ob = __shfl_xor(best[s], m);
            int   oi = __shfl_xor(bidx[s], m);
            float os = __shfl_xor(sec[s], m);
            if (ob < best[s] || (ob == best[s] && oi < bidx[s])) {
                sec[s]  = fminf(best[s], os);
                best[s] = ob; bidx[s] = oi;
            } else {
                sec[s]  = fminf(sec[s], ob);
            }
        }
    }
    __syncthreads();
    float* mg = (float*)smem;
    if (cl == 0) {
        #pragma unroll
        for (int mt = 0; mt < 4; ++mt)
            #pragma unroll
            for (int r = 0; r < 4; ++r) {
                int row = wm + mt * 16 + kq * 4 + r;
                int o = ((wn >> 6) * 128 + row) * 4;
                mg[o + 0] = best[mt * 4 + r];
                mg[o + 1] = __int_as_float(bidx[mt * 4 + r]);
                mg[o + 2] = sec[mt * 4 + r];
            }
    }
    __syncthreads();
    if (tid < MT) {
        float b0 = mg[tid * 4],         s0v = mg[tid * 4 + 2];
        int   i0 = __float_as_int(mg[tid * 4 + 1]);
        float b1 = mg[(128 + tid) * 4], s1v = mg[(128 + tid) * 4 + 2];
        int   i1 = __float_as_int(mg[(128 + tid) * 4 + 1]);
        float B, S; int I;
        if (b1 < b0 || (b1 == b0 && i1 < i0)) { B = b1; I = i1; S = fminf(s1v, b0); }
        else                                   { B = b0; I = i0; S = fminf(s0v, b1); }
        partial[(size_t)split * N_TOK + m0 + tid] = make_float4(B, __int_as_float(I), S, 0.f);
    }
}

extern "C" void kernel_launch(void* const* d_in, const int* in_sizes, int n_in,
                              void* d_out, int out_size, void* d_ws, size_t ws_size,
                              hipStream_t stream) {
    const float* ze = (const float*)d_in[0];
    const float* cb = (const float*)d_in[1];

    float* out      = (float*)d_out;
    float* out_zq   = out;
    float* out_idx  = out + (size_t)N_TOK * DD;
    float* out_loss = out_idx + N_TOK;

    char*   ws    = (char*)d_ws;
    float*  cnorm = (float*)ws;                     // 32 KB
    int*    idxi  = (int*)(ws + 32768);             // 128 KB
    double* accum = (double*)(ws + 163840);
    int*    flagc = (int*)(ws + 163848);
    int*    flagc2= (int*)(ws + 163852);
    int*    flag_list = (int*)(ws + 163856);        // 32 KB
    int*    list2     = (int*)(ws + 196624);        // 16 KB

    const size_t OFF_ZEF  = 213008;
    const size_t OFF_CBF  = OFF_ZEF + (size_t)N_TOK * DD * 2;     // +16.78 MB
    const size_t OFF_P1   = OFF_CBF + (size_t)KC * DD * 2;        // +4.19 MB
    const size_t OFF_P2   = OFF_P1 + (size_t)CSPL * N_TOK * 16;   // +1.05 MB
    const size_t NEED     = OFF_P2 + 16ull * FLAG_CAP * 16;       // ~24.4 MB

    if (ws_size >= NEED) {
        _Float16* zef = (_Float16*)(ws + OFF_ZEF);
        _Float16* cbf = (_Float16*)(ws + OFF_CBF);
        float4* partial  = (float4*)(ws + OFF_P1);
        float4* partial2 = (float4*)(ws + OFF_P2);

        hipLaunchKernelGGL(k_cnorm, dim3(KC / 4), dim3(256), 0, stream,
                           cb, cnorm, accum, flagc, flagc2, cbf);
        hipLaunchKernelGGL(k_convert_ze, dim3(N_TOK * DD / 8 / 256), dim3(256), 0, stream,
                           ze, zef, N_TOK * DD / 8);
        hipLaunchKernelGGL(k_argmin_f16, dim3(N_TOK / MT, CSPL), dim3(256), 0, stream,
                           zef, cbf, cnorm, partial);
        hipLaunchKernelGGL(k_combine, dim3(N_TOK / 256), dim3(256), 0, stream,
                           partial, idxi, out_idx, flagc, flag_list, CSPL, EPS1, FLAG_CAP);
        hipLaunchKernelGGL(k_argmin2, dim3(FLAG_CAP / 64, 16), dim3(256), 0, stream,
                           ze, cb, cnorm, flag_list, flagc, partial2);
        hipLaunchKernelGGL(k_combine2, dim3(FLAG_CAP / 256), dim3(256), 0, stream,
                           partial2, flag_list, flagc, idxi, out_idx, flagc2, list2);
        hipLaunchKernelGGL(k_rescore, dim3(128), dim3(256), 0, stream,
                           ze, cb, cnorm, flagc2, list2, idxi, out_idx, CAP2);
    } else {
        hipLaunchKernelGGL(k_cnorm, dim3(KC / 4), dim3(256), 0, stream,
                           cb, cnorm, accum, flagc, flagc2, (_Float16*)0);
        float4* partial = (float4*)d_out;
        int* fl = (int*)(ws + 163856);
        hipLaunchKernelGGL(k_argmin_fb, dim3(N_TOK / MT, 16), dim3(256), 0, stream,
                           ze, cb, cnorm, partial);
        hipLaunchKernelGGL(k_combine, dim3(N_TOK / 256), dim3(256), 0, stream,
                           partial, idxi, out_idx, flagc, fl, 16, EPS2, FLAG_CAP);
        hipLaunchKernelGGL(k_rescore, dim3(128), dim3(256), 0, stream,
                           ze, cb, cnorm, flagc, fl, idxi, out_idx, FLAG_CAP);
    }

    hipLaunchKernelGGL(k_gather, dim3(N_TOK / 16), dim3(256), 0, stream, ze, cb, idxi, out_zq, accum);
    hipLaunchKernelGGL(k_final,  dim3(1), dim3(1), 0, stream, accum, out_loss);
}

// Round 6
// 417.759 us; speedup vs baseline: 2.9447x; 1.3902x over previous
//
#include <hip/hip_runtime.h>

// VectorQuantizer: N=32768 tokens, K=8192 codes, D=256, fp32 in/out.
// Outputs (concat, float): z_q_ste[32768*256], idx[32768] (as float), loss[1].
// R6: same as R5 (A-in-regs fp16 GEMM + cascade), but the exact fp32 rescore
// is split over codes (grid y = 32 code-splits) so ~3 flagged tokens use ~96
// CUs instead of 3 (R5: 239 us single-CU memory crawl).

#define N_TOK   32768
#define KC      8192
#define DD      256
#define D4      64
#define CSPL    2               // code splits for stage-1
#define MT      128
#define EPS1    0.025f
#define EPS2    1e-3f
#define FLAG_CAP 8192
#define CAP2     4096
#define ASTR    40

typedef __bf16    bf16x8 __attribute__((ext_vector_type(8)));
typedef _Float16  f16x8  __attribute__((ext_vector_type(8)));
typedef _Float16  f16x4  __attribute__((ext_vector_type(4)));
typedef float     f32x4  __attribute__((ext_vector_type(4)));

#define GLL(gp, lp) __builtin_amdgcn_global_load_lds(                                   \
    (const __attribute__((address_space(1))) void*)(unsigned long long)(uintptr_t)(gp), \
    (__attribute__((address_space(3))) void*)(unsigned)(uintptr_t)(lp), 16, 0, 0)

#define PK(a, b, HO, LO) do {                                   \
    unsigned ua = __float_as_uint(a), ub = __float_as_uint(b);  \
    unsigned ham = ua & 0xFFFF0000u, hbm = ub & 0xFFFF0000u;    \
    float la = (a) - __uint_as_float(ham);                      \
    float lb = (b) - __uint_as_float(hbm);                      \
    HO = (ua >> 16) | hbm;                                      \
    LO = (__float_as_uint(la) >> 16) | (__float_as_uint(lb) & 0xFFFF0000u); \
} while (0)

// ---------------- kernel 1: code norms + cb->f16 + zero accumulators ----------------
__global__ __launch_bounds__(256)
void k_cnorm(const float* __restrict__ cb, float* __restrict__ cnorm,
             double* __restrict__ accum, int* __restrict__ flagc,
             int* __restrict__ flagc2, _Float16* __restrict__ cbf16) {
    if (blockIdx.x == 0 && threadIdx.x == 0) { *accum = 0.0; *flagc = 0; *flagc2 = 0; }
    const int gid  = blockIdx.x * 256 + threadIdx.x;
    const int code = gid >> 6;
    const int lane = threadIdx.x & 63;
    if (code < KC) {
        float4 v = ((const float4*)cb)[code * D4 + lane];
        if (cbf16) {
            f16x4 h;
            h[0] = (_Float16)v.x; h[1] = (_Float16)v.y;
            h[2] = (_Float16)v.z; h[3] = (_Float16)v.w;
            *(f16x4*)(cbf16 + (size_t)code * DD + lane * 4) = h;
        }
        float s = v.x*v.x + v.y*v.y + v.z*v.z + v.w*v.w;
        #pragma unroll
        for (int off = 32; off > 0; off >>= 1) s += __shfl_down(s, off);
        if (lane == 0) cnorm[code] = s;
    }
}

// ---------------- kernel 2: z_e -> fp16 ----------------
__global__ __launch_bounds__(256)
void k_convert_ze(const float* __restrict__ src, _Float16* __restrict__ dst, int n8) {
    int t = blockIdx.x * 256 + threadIdx.x;
    if (t >= n8) return;
    const float4* s = (const float4*)src;
    float4 v0 = s[2 * t], v1 = s[2 * t + 1];
    f16x8 h;
    h[0] = (_Float16)v0.x; h[1] = (_Float16)v0.y; h[2] = (_Float16)v0.z; h[3] = (_Float16)v0.w;
    h[4] = (_Float16)v1.x; h[5] = (_Float16)v1.y; h[6] = (_Float16)v1.z; h[7] = (_Float16)v1.w;
    ((f16x8*)dst)[t] = h;
}

// ---------------- kernel 3: stage-1 fp16 GEMM, A-in-regs + B dbuf stream ----------------
__global__ __launch_bounds__(256)
void k_argmin_f16(const _Float16* __restrict__ zef, const _Float16* __restrict__ cbf,
                  const float* __restrict__ cnorm, float4* __restrict__ partial) {
    // LDS: phase 1: A tile 128 rows x 512 B (64 KB). phase 2: B dbuf 2 x 32 KB.
    // XOR swizzle: 16B chunk (row, c) stored at row*512 + ((c ^ (row&31))<<4).
    __shared__ __align__(16) char smem[65536];

    const int tid  = threadIdx.x;
    const int lane = tid & 63;
    const int wid  = tid >> 6;
    const int cl   = lane & 15;
    const int kq   = lane >> 4;
    const int m0   = blockIdx.x * MT;
    const int split = blockIdx.y;
    const int c0b  = split * (KC / CSPL);      // 4096 codes per split
    const int wrow0 = wid * 32;                // wave's 32 token rows

    // ---- phase 1: stage full-K A tile once, pull fragments into registers ----
    {
        const int lr = lane >> 5;              // 0..1 row within 1KB GLL
        const int lc = lane & 31;              // swizzled chunk
        #pragma unroll
        for (int j = 0; j < 16; ++j) {
            int I = wid * 16 + j;              // 0..63 -> rows 2I, 2I+1
            int r = 2 * I + lr;
            int c = lc ^ (r & 31);
            GLL((const char*)zef + (size_t)(m0 + r) * 512 + c * 16, smem + I * 1024);
        }
    }
    __syncthreads();
    f16x8 afr[2][8];
    #pragma unroll
    for (int mt = 0; mt < 2; ++mt)
        #pragma unroll
        for (int ks = 0; ks < 8; ++ks) {
            int row = wrow0 + mt * 16 + cl;
            int c   = ks * 4 + kq;
            afr[mt][ks] = *(const f16x8*)(smem + row * 512 + (((c ^ (row & 31))) << 4));
        }
    __syncthreads();                           // A LDS free -> becomes B dbuf

    // ---- phase 2: stream B (64 codes x full K per ch), dbuf + early prefetch ----
    char* bbuf0 = smem;
    char* bbuf1 = smem + 32768;
    const int lr = lane >> 5;
    const int lc = lane & 31;

    // stage ch=0 into bbuf0
    #pragma unroll
    for (int j = 0; j < 8; ++j) {
        int I = wid * 8 + j;                   // 0..31 -> rows 2I, 2I+1 (codes)
        int r = 2 * I + lr;
        int c = lc ^ (r & 31);
        GLL((const char*)cbf + (size_t)(c0b + r) * 512 + c * 16, bbuf0 + I * 1024);
    }
    __syncthreads();

    float best[8], sec[8]; int bidx[8];
    #pragma unroll
    for (int s = 0; s < 8; ++s) { best[s] = 3.4e38f; sec[s] = 3.4e38f; bidx[s] = 0; }

    for (int ch = 0; ch < 64; ++ch) {
        char* cur = (ch & 1) ? bbuf1 : bbuf0;
        char* nxt = (ch & 1) ? bbuf0 : bbuf1;
        if (ch < 63) {                         // prefetch ch+1 a full iteration early
            const int cr0 = c0b + (ch + 1) * 64;
            #pragma unroll
            for (int j = 0; j < 8; ++j) {
                int I = wid * 8 + j;
                int r = 2 * I + lr;
                int c = lc ^ (r & 31);
                GLL((const char*)cbf + (size_t)(cr0 + r) * 512 + c * 16, nxt + I * 1024);
            }
        }

        f32x4 acc[2][4];
        #pragma unroll
        for (int mt = 0; mt < 2; ++mt)
            #pragma unroll
            for (int nt = 0; nt < 4; ++nt)
                acc[mt][nt] = (f32x4){0.f, 0.f, 0.f, 0.f};

        #pragma unroll
        for (int ks = 0; ks < 8; ++ks) {
            f16x8 bfr[4];
            #pragma unroll
            for (int nt = 0; nt < 4; ++nt) {
                int row = nt * 16 + cl;
                int c   = ks * 4 + kq;
                bfr[nt] = *(const f16x8*)(cur + row * 512 + ((c ^ (row & 31)) << 4));
            }
            #pragma unroll
            for (int mt = 0; mt < 2; ++mt)
                #pragma unroll
                for (int nt = 0; nt < 4; ++nt)
                    acc[mt][nt] = __builtin_amdgcn_mfma_f32_16x16x32_f16(afr[mt][ks], bfr[nt], acc[mt][nt], 0, 0, 0);
        }

        // fold into running top-2 (codes ascend across ch and nt: '<' keeps first idx)
        const int cc0 = c0b + ch * 64;
        #pragma unroll
        for (int nt = 0; nt < 4; ++nt) {
            const int code = cc0 + nt * 16 + cl;
            const float cn = cnorm[code];
            #pragma unroll
            for (int mt = 0; mt < 2; ++mt)
                #pragma unroll
                for (int r = 0; r < 4; ++r) {
                    float dist = fmaf(-2.f, acc[mt][nt][r], cn);
                    int s = mt * 4 + r;
                    bool lt = dist < best[s];
                    sec[s] = lt ? best[s] : fminf(sec[s], dist);
                    if (lt) { best[s] = dist; bidx[s] = code; }
                }
        }
        __syncthreads();                       // drains prefetch (issued ~600cyc ago) + buf reuse
    }

    // reduce over the 16 col-lanes (cl); masks < 16 stay within kq group
    #pragma unroll
    for (int m = 1; m < 16; m <<= 1) {
        #pragma unroll
        for (int s = 0; s < 8; ++s) {
            float ob = __shfl_xor(best[s], m);
            int   oi = __shfl_xor(bidx[s], m);
            float os = __shfl_xor(sec[s], m);
            if (ob < best[s] || (ob == best[s] && oi < bidx[s])) {
                sec[s]  = fminf(best[s], os);
                best[s] = ob; bidx[s] = oi;
            } else {
                sec[s]  = fminf(sec[s], ob);
            }
        }
    }
    if (cl == 0) {                             // lanes kq*16: own rows wrow0+mt*16+kq*4+r
        #pragma unroll
        for (int mt = 0; mt < 2; ++mt)
            #pragma unroll
            for (int r = 0; r < 4; ++r) {
                int row = wrow0 + mt * 16 + kq * 4 + r;
                int s = mt * 4 + r;
                partial[(size_t)split * N_TOK + m0 + row] =
                    make_float4(best[s], __int_as_float(bidx[s]), sec[s], 0.f);
            }
    }
}

// ---------------- kernel 4: combine splits, emit idx + flag list ----------------
__global__ __launch_bounds__(256)
void k_combine(const float4* __restrict__ partial, int* __restrict__ idxi,
               float* __restrict__ idxf, int* __restrict__ flagc,
               int* __restrict__ flag_list, int splits, float eps, int cap) {
    const int t = blockIdx.x * 256 + threadIdx.x;
    float B = 3.4e38f, S = 3.4e38f; int I = 0;
    for (int s = 0; s < splits; ++s) {
        float4 p = partial[(size_t)s * N_TOK + t];
        int oi = __float_as_int(p.y);
        if (p.x < B || (p.x == B && oi < I)) { S = fminf(B, p.z); B = p.x; I = oi; }
        else                                  { S = fminf(S, p.x); }
    }
    idxi[t] = I;
    idxf[t] = (float)I;
    if (S - B < eps) {
        int pos = atomicAdd(flagc, 1);
        if (pos < cap) flag_list[pos] = t;
    }
}

// float8 -> bf16 hi/lo staging (for stage-2 and fallback)
__device__ __forceinline__ void stage8(const float* __restrict__ gp,
                                       ushort* __restrict__ h, ushort* __restrict__ l) {
    float4 v0 = *(const float4*)gp;
    float4 v1 = *(const float4*)(gp + 4);
    uint4 hp, lp;
    PK(v0.x, v0.y, hp.x, lp.x);
    PK(v0.z, v0.w, hp.y, lp.y);
    PK(v1.x, v1.y, hp.z, lp.z);
    PK(v1.z, v1.w, hp.w, lp.w);
    *(uint4*)h = hp;
    *(uint4*)l = lp;
}

// ---------------- kernel 5: gathered bf16 3-term rescore GEMM (flagged tokens) ----------------
__global__ __launch_bounds__(256, 2)
void k_argmin2(const float* __restrict__ ze, const float* __restrict__ cb,
               const float* __restrict__ cnorm, const int* __restrict__ flag_list,
               const int* __restrict__ flagc, float4* __restrict__ partial2) {
    int nf = flagc[0]; if (nf > FLAG_CAP) nf = FLAG_CAP;
    const int m0 = blockIdx.x * 64;
    if (m0 >= nf) return;

    __shared__ ushort smem2[(64 + 64 + 256 + 256) * ASTR];
    ushort* Ah = smem2;
    ushort* Al = Ah + 64 * ASTR;
    ushort* Bh = Al + 64 * ASTR;
    ushort* Bl = Bh + 256 * ASTR;

    const int tid  = threadIdx.x;
    const int lane = tid & 63;
    const int wid  = tid >> 6;
    const int cl   = lane & 15;
    const int kq   = lane >> 4;
    const int wn   = wid * 64;
    const int split = blockIdx.y;

    const int r0 = tid >> 2;
    const int g0 = (tid & 3) * 8;
    int tokr = m0 + r0; if (tokr > nf - 1) tokr = nf - 1;
    const int tok = flag_list[tokr];
    const float* zeA = ze + (size_t)tok * DD + g0;

    const int boff = (wn + cl) * ASTR + kq * 8;

    float best[16], sec[16]; int bidx[16];
    #pragma unroll
    for (int s = 0; s < 16; ++s) { best[s] = 3.4e38f; sec[s] = 3.4e38f; bidx[s] = 0; }

    for (int ch = 0; ch < 2; ++ch) {
        const int c0 = split * 512 + ch * 256;
        const float* cbB = cb + (size_t)(c0 + r0) * DD + g0;
        f32x4 acc[4][4];
        #pragma unroll
        for (int mt = 0; mt < 4; ++mt)
            #pragma unroll
            for (int nt = 0; nt < 4; ++nt)
                acc[mt][nt] = (f32x4){0.f, 0.f, 0.f, 0.f};

        for (int ks = 0; ks < 8; ++ks) {
            __syncthreads();
            stage8(zeA + ks * 32, Ah + r0 * ASTR + g0, Al + r0 * ASTR + g0);
            #pragma unroll
            for (int rep = 0; rep < 4; ++rep)
                stage8(cbB + (size_t)rep * 64 * DD + ks * 32,
                       Bh + (r0 + rep * 64) * ASTR + g0, Bl + (r0 + rep * 64) * ASTR + g0);
            __syncthreads();

            bf16x8 bh[4], bl[4];
            #pragma unroll
            for (int nt = 0; nt < 4; ++nt) {
                bh[nt] = *(const bf16x8*)(Bh + boff + nt * 16 * ASTR);
                bl[nt] = *(const bf16x8*)(Bl + boff + nt * 16 * ASTR);
            }
            #pragma unroll
            for (int mt = 0; mt < 4; ++mt) {
                const int ao = (mt * 16 + cl) * ASTR + kq * 8;
                bf16x8 ah = *(const bf16x8*)(Ah + ao);
                bf16x8 al = *(const bf16x8*)(Al + ao);
                #pragma unroll
                for (int nt = 0; nt < 4; ++nt) {
                    acc[mt][nt] = __builtin_amdgcn_mfma_f32_16x16x32_bf16(ah, bh[nt], acc[mt][nt], 0, 0, 0);
                    acc[mt][nt] = __builtin_amdgcn_mfma_f32_16x16x32_bf16(ah, bl[nt], acc[mt][nt], 0, 0, 0);
                    acc[mt][nt] = __builtin_amdgcn_mfma_f32_16x16x32_bf16(al, bh[nt], acc[mt][nt], 0, 0, 0);
                }
            }
        }
        #pragma unroll
        for (int nt = 0; nt < 4; ++nt) {
            const int code = c0 + wn + nt * 16 + cl;
            const float cn = cnorm[code];
            #pragma unroll
            for (int mt = 0; mt < 4; ++mt)
                #pragma unroll
                for (int r = 0; r < 4; ++r) {
                    float dist = fmaf(-2.f, acc[mt][nt][r], cn);
                    int s = mt * 4 + r;
                    bool lt = dist < best[s];
                    sec[s] = lt ? best[s] : fminf(sec[s], dist);
                    if (lt) { best[s] = dist; bidx[s] = code; }
                }
        }
    }

    #pragma unroll
    for (int m = 1; m < 16; m <<= 1) {
        #pragma unroll
        for (int s = 0; s < 16; ++s) {
            float ob = __shfl_xor(best[s], m);
            int   oi = __shfl_xor(bidx[s], m);
            float os = __shfl_xor(sec[s], m);
            if (ob < best[s] || (ob == best[s] && oi < bidx[s])) {
                sec[s]  = fminf(best[s], os);
                best[s] = ob; bidx[s] = oi;
            } else {
                sec[s]  = fminf(sec[s], ob);
            }
        }
    }
    __syncthreads();
    float* mg = (float*)smem2;
    if (cl == 0) {
        #pragma unroll
        for (int mt = 0; mt < 4; ++mt)
            #pragma unroll
            for (int r = 0; r < 4; ++r) {
                int row = mt * 16 + kq * 4 + r;
                int o = (wid * 64 + row) * 4;
                mg[o + 0] = best[mt * 4 + r];
                mg[o + 1] = __int_as_float(bidx[mt * 4 + r]);
                mg[o + 2] = sec[mt * 4 + r];
            }
    }
    __syncthreads();
    if (tid < 64 && m0 + tid < nf) {
        float B = 3.4e38f, S = 3.4e38f; int I = 0;
        #pragma unroll
        for (int j = 0; j < 4; ++j) {
            float b = mg[(j * 64 + tid) * 4];
            int   i = __float_as_int(mg[(j * 64 + tid) * 4 + 1]);
            float s = mg[(j * 64 + tid) * 4 + 2];
            if (b < B || (b == B && i < I)) { S = fminf(B, s); B = b; I = i; }
            else                             { S = fminf(S, b); }
        }
        partial2[(size_t)split * FLAG_CAP + m0 + tid] = make_float4(B, __int_as_float(I), S, 0.f);
    }
}

// ---------------- kernel 6: combine stage-2 splits ----------------
__global__ __launch_bounds__(256)
void k_combine2(const float4* __restrict__ partial2, const int* __restrict__ flag_list,
                const int* __restrict__ flagc, int* __restrict__ idxi,
                float* __restrict__ idxf, int* __restrict__ flagc2,
                int* __restrict__ list2) {
    int nf = flagc[0]; if (nf > FLAG_CAP) nf = FLAG_CAP;
    const int f = blockIdx.x * 256 + threadIdx.x;
    if (f >= nf) return;
    float B = 3.4e38f, S = 3.4e38f; int I = 0;
    #pragma unroll
    for (int s = 0; s < 16; ++s) {
        float4 p = partial2[(size_t)s * FLAG_CAP + f];
        int oi = __float_as_int(p.y);
        if (p.x < B || (p.x == B && oi < I)) { S = fminf(B, p.z); B = p.x; I = oi; }
        else                                  { S = fminf(S, p.x); }
    }
    const int t = flag_list[f];
    idxi[t] = I;
    idxf[t] = (float)I;
    if (S - B < EPS2) {
        int pos = atomicAdd(flagc2, 1);
        if (pos < CAP2) list2[pos] = t;
    }
}

// ---------------- kernel 7a: exact fp32 rescore, code-split partials ----------------
// grid (64, 32): block scores codes [by*256, by*256+256) for tokens f = bx, bx+64, ...
__global__ __launch_bounds__(256)
void k_rescore_part(const float* __restrict__ ze, const float* __restrict__ cb,
                    const float* __restrict__ cnorm, const int* __restrict__ flagc,
                    const int* __restrict__ flag_list, float2* __restrict__ part3,
                    int cap) {
    __shared__ float xsh[DD];
    __shared__ float2 red[256];
    const int tid = threadIdx.x;
    const int cs  = blockIdx.y;
    int nf = flagc[0]; if (nf > cap) nf = cap;
    for (int f = blockIdx.x; f < nf; f += gridDim.x) {
        const int t = flag_list[f];
        if (tid < 64) *(float4*)&xsh[tid * 4] = ((const float4*)ze)[(size_t)t * D4 + tid];
        __syncthreads();
        const int c = cs * 256 + tid;          // one code per thread
        const float4* cr = (const float4*)(cb + (size_t)c * DD);
        float dot = 0.f;
        #pragma unroll 8
        for (int j = 0; j < D4; ++j) {
            float4 cv = cr[j];
            float4 xv = *(const float4*)&xsh[j * 4];
            dot = fmaf(cv.x, xv.x, dot);
            dot = fmaf(cv.y, xv.y, dot);
            dot = fmaf(cv.z, xv.z, dot);
            dot = fmaf(cv.w, xv.w, dot);
        }
        red[tid] = make_float2(fmaf(-2.f, dot, cnorm[c]), __int_as_float(c));
        __syncthreads();
        for (int s = 128; s > 0; s >>= 1) {
            if (tid < s) {
                float2 o = red[tid + s], me = red[tid];
                int oi = __float_as_int(o.y), mi = __float_as_int(me.y);
                if (o.x < me.x || (o.x == me.x && oi < mi)) red[tid] = o;
            }
            __syncthreads();
        }
        if (tid == 0) part3[(size_t)f * 32 + cs] = red[0];
        __syncthreads();
    }
}

// ---------------- kernel 7b: fold code-split partials ----------------
__global__ __launch_bounds__(256)
void k_rescore_fin(const float2* __restrict__ part3, const int* __restrict__ flagc,
                   const int* __restrict__ flag_list, int* __restrict__ idxi,
                   float* __restrict__ idxf, int cap) {
    int nf = flagc[0]; if (nf > cap) nf = cap;
    const int f = blockIdx.x * 256 + threadIdx.x;
    if (f >= nf) return;
    float B = 3.4e38f; int I = 0;
    #pragma unroll
    for (int s = 0; s < 32; ++s) {             // splits ascend in code: first-min kept
        float2 p = part3[(size_t)f * 32 + s];
        int oi = __float_as_int(p.y);
        if (p.x < B || (p.x == B && oi < I)) { B = p.x; I = oi; }
    }
    const int t = flag_list[f];
    idxi[t] = I;
    idxf[t] = (float)I;
}

// ---------------- kernel 7 (fallback path): monolithic exact fp32 rescore ----------------
__global__ __launch_bounds__(256)
void k_rescore(const float* __restrict__ ze, const float* __restrict__ cb,
               const float* __restrict__ cnorm, const int* __restrict__ flagc,
               const int* __restrict__ flag_list, int* __restrict__ idxi,
               float* __restrict__ idxf, int cap) {
    __shared__ float xsh[DD];
    __shared__ float2 red[256];
    const int tid = threadIdx.x;
    int nf = flagc[0]; if (nf > cap) nf = cap;
    for (int f = blockIdx.x; f < nf; f += gridDim.x) {
        const int t = flag_list[f];
        if (tid < 64) *(float4*)&xsh[tid * 4] = ((const float4*)ze)[(size_t)t * D4 + tid];
        __syncthreads();
        float B = 3.4e38f; int I = 0;
        for (int c = tid; c < KC; c += 256) {
            const float4* cr = (const float4*)(cb + (size_t)c * DD);
            float dot = 0.f;
            #pragma unroll 8
            for (int j = 0; j < D4; ++j) {
                float4 cv = cr[j];
                float4 xv = *(const float4*)&xsh[j * 4];
                dot = fmaf(cv.x, xv.x, dot);
                dot = fmaf(cv.y, xv.y, dot);
                dot = fmaf(cv.z, xv.z, dot);
                dot = fmaf(cv.w, xv.w, dot);
            }
            float dist = fmaf(-2.f, dot, cnorm[c]);
            if (dist < B) { B = dist; I = c; }
        }
        red[tid] = make_float2(B, __int_as_float(I));
        __syncthreads();
        for (int s = 128; s > 0; s >>= 1) {
            if (tid < s) {
                float2 o = red[tid + s], me = red[tid];
                int oi = __float_as_int(o.y), mi = __float_as_int(me.y);
                if (o.x < me.x || (o.x == me.x && oi < mi)) red[tid] = o;
            }
            __syncthreads();
        }
        if (tid == 0) { int I2 = __float_as_int(red[0].y); idxi[t] = I2; idxf[t] = (float)I2; }
        __syncthreads();
    }
}

// ---------------- kernel 8: gather + STE output + loss partial ----------------
__global__ __launch_bounds__(256)
void k_gather(const float* __restrict__ ze, const float* __restrict__ cb,
              const int* __restrict__ idxi, float* __restrict__ zq,
              double* __restrict__ accum) {
    const int tid = threadIdx.x;
    const int t0  = blockIdx.x * 16;
    double dsum = 0.0;
    #pragma unroll
    for (int i = 0; i < 4; ++i) {
        int f = tid + i * 256;
        int row = f >> 6, e = f & 63;
        int t = t0 + row;
        int code = idxi[t];
        float4 zev = ((const float4*)ze)[(size_t)t * D4 + e];
        float4 cbv = ((const float4*)cb)[(size_t)code * D4 + e];
        float dx = cbv.x - zev.x, dy = cbv.y - zev.y;
        float dz = cbv.z - zev.z, dw = cbv.w - zev.w;
        float4 o;
        o.x = zev.x + dx; o.y = zev.y + dy; o.z = zev.z + dz; o.w = zev.w + dw;
        ((float4*)zq)[(size_t)t * D4 + e] = o;
        dsum += (double)dx * dx + (double)dy * dy + (double)dz * dz + (double)dw * dw;
    }
    #pragma unroll
    for (int off = 32; off > 0; off >>= 1) dsum += __shfl_down(dsum, off);
    __shared__ double wsum[4];
    if ((tid & 63) == 0) wsum[tid >> 6] = dsum;
    __syncthreads();
    if (tid == 0) atomicAdd(accum, wsum[0] + wsum[1] + wsum[2] + wsum[3]);
}

// ---------------- kernel 9: finalize loss ----------------
__global__ void k_final(const double* __restrict__ accum, float* __restrict__ loss) {
    loss[0] = (float)(accum[0] * (1.25 / 8388608.0));
}

// ---------------- fallback: R2-style 3-term in-loop-conversion GEMM ----------------
__global__ __launch_bounds__(256, 2)
void k_argmin_fb(const float* __restrict__ ze, const float* __restrict__ cb,
                 const float* __restrict__ cnorm, float4* __restrict__ partial) {
    __shared__ ushort smem[4 * 128 * ASTR];
    ushort* Ah = smem;
    ushort* Al = smem + 128 * ASTR;
    ushort* Bh = smem + 2 * 128 * ASTR;
    ushort* Bl = smem + 3 * 128 * ASTR;

    const int tid  = threadIdx.x;
    const int lane = tid & 63;
    const int wid  = tid >> 6;
    const int cl   = lane & 15;
    const int kq   = lane >> 4;
    const int wm   = (wid & 1) * 64;
    const int wn   = (wid >> 1) * 64;
    const int m0   = blockIdx.x * MT;
    const int split = blockIdx.y;

    const int r0 = tid >> 2;
    const int g0 = (tid & 3) * 8;
    const float* zeA = ze + (size_t)(m0 + r0) * DD + g0;
    const int aoff = (wm + cl) * ASTR + kq * 8;
    const int boff = (wn + cl) * ASTR + kq * 8;

    float best[16], sec[16]; int bidx[16];
    #pragma unroll
    for (int s = 0; s < 16; ++s) { best[s] = 3.4e38f; sec[s] = 3.4e38f; bidx[s] = 0; }

    for (int ch = 0; ch < 4; ++ch) {
        const int c0 = split * 512 + ch * 128;
        const float* cbB = cb + (size_t)(c0 + r0) * DD + g0;
        f32x4 acc[4][4];
        #pragma unroll
        for (int mt = 0; mt < 4; ++mt)
            #pragma unroll
            for (int nt = 0; nt < 4; ++nt)
                acc[mt][nt] = (f32x4){0.f, 0.f, 0.f, 0.f};

        for (int ks = 0; ks < 8; ++ks) {
            __syncthreads();
            stage8(zeA + ks * 32,            Ah + r0 * ASTR + g0, Al + r0 * ASTR + g0);
            stage8(zeA + 64 * DD + ks * 32,  Ah + (r0 + 64) * ASTR + g0, Al + (r0 + 64) * ASTR + g0);
            stage8(cbB + ks * 32,            Bh + r0 * ASTR + g0, Bl + r0 * ASTR + g0);
            stage8(cbB + 64 * DD + ks * 32,  Bh + (r0 + 64) * ASTR + g0, Bl + (r0 + 64) * ASTR + g0);
            __syncthreads();

            bf16x8 bh[4], bl[4];
            #pragma unroll
            for (int nt = 0; nt < 4; ++nt) {
                bh[nt] = *(const bf16x8*)(Bh + boff + nt * 16 * ASTR);
                bl[nt] = *(const bf16x8*)(Bl + boff + nt * 16 * ASTR);
            }
            #pragma unroll
            for (int mt = 0; mt < 4; ++mt) {
                bf16x8 ah = *(const bf16x8*)(Ah + aoff + mt * 16 * ASTR);
                bf16x8 al = *(const bf16x8*)(Al + aoff + mt * 16 * ASTR);
                #pragma unroll
                for (int nt = 0; nt < 4; ++nt) {
                    acc[mt][nt] = __builtin_amdgcn_mfma_f32_16x16x32_bf16(ah, bh[nt], acc[mt][nt], 0, 0, 0);
                    acc[mt][nt] = __builtin_amdgcn_mfma_f32_16x16x32_bf16(ah, bl[nt], acc[mt][nt], 0, 0, 0);
                    acc[mt][nt] = __builtin_amdgcn_mfma_f32_16x16x32_bf16(al, bh[nt], acc[mt][nt], 0, 0, 0);
                }
            }
        }
        #pragma unroll
        for (int nt = 0; nt < 4; ++nt) {
            const int code = c0 + wn + nt * 16 + cl;
            const float cn = cnorm[code];
            #pragma unroll
            for (int mt = 0; mt < 4; ++mt)
                #pragma unroll
                for (int r = 0; r < 4; ++r) {
                    float dist = fmaf(-2.f, acc[mt][nt][r], cn);
                    int s = mt * 4 + r;
                    bool lt = dist < best[s];
                    sec[s] = lt ? best[s] : fminf(sec[s], dist);
                    if (lt) { best[s] = dist; bidx[s] = code; }
                }
        }
    }

    #pragma unroll
    for (int m = 1; m < 16; m <<= 1) {
        #pragma unroll
        for (int s = 0; s < 16; ++s) {
            float ob = __shfl_xor(best[s], m);
            int   oi = __shfl_xor(bidx[s], m);
            float os = __shfl_xor(sec[s], m);
            if (ob < best[s] || (ob == best[s] && oi < bidx[s])) {
                sec[s]  = fminf(best[s], os);
                best[s] = ob; bidx[s] = oi;
            } else {
                sec[s]  = fminf(sec[s], ob);
            }
        }
    }
    __syncthreads();
    float* mg = (float*)smem;
    if (cl == 0) {
        #pragma unroll
        for (int mt = 0; mt < 4; ++mt)
            #pragma unroll
            for (int r = 0; r < 4; ++r) {
                int row = wm + mt * 16 + kq * 4 + r;
                int o = ((wn >> 6) * 128 + row) * 4;
                mg[o + 0] = best[mt * 4 + r];
                mg[o + 1] = __int_as_float(bidx[mt * 4 + r]);
                mg[o + 2] = sec[mt * 4 + r];
            }
    }
    __syncthreads();
    if (tid < MT) {
        float b0 = mg[tid * 4],         s0v = mg[tid * 4 + 2];
        int   i0 = __float_as_int(mg[tid * 4 + 1]);
        float b1 = mg[(128 + tid) * 4], s1v = mg[(128 + tid) * 4 + 2];
        int   i1 = __float_as_int(mg[(128 + tid) * 4 + 1]);
        float B, S; int I;
        if (b1 < b0 || (b1 == b0 && i1 < i0)) { B = b1; I = i1; S = fminf(s1v, b0); }
        else                                   { B = b0; I = i0; S = fminf(s0v, b1); }
        partial[(size_t)split * N_TOK + m0 + tid] = make_float4(B, __int_as_float(I), S, 0.f);
    }
}

extern "C" void kernel_launch(void* const* d_in, const int* in_sizes, int n_in,
                              void* d_out, int out_size, void* d_ws, size_t ws_size,
                              hipStream_t stream) {
    const float* ze = (const float*)d_in[0];
    const float* cb = (const float*)d_in[1];

    float* out      = (float*)d_out;
    float* out_zq   = out;
    float* out_idx  = out + (size_t)N_TOK * DD;
    float* out_loss = out_idx + N_TOK;

    char*   ws    = (char*)d_ws;
    float*  cnorm = (float*)ws;                     // 32 KB
    int*    idxi  = (int*)(ws + 32768);             // 128 KB
    double* accum = (double*)(ws + 163840);
    int*    flagc = (int*)(ws + 163848);
    int*    flagc2= (int*)(ws + 163852);
    int*    flag_list = (int*)(ws + 163856);        // 32 KB
    int*    list2     = (int*)(ws + 196624);        // 16 KB

    const size_t OFF_ZEF  = 213008;
    const size_t OFF_CBF  = OFF_ZEF + (size_t)N_TOK * DD * 2;     // +16.78 MB
    const size_t OFF_P1   = OFF_CBF + (size_t)KC * DD * 2;        // +4.19 MB
    const size_t OFF_P2   = OFF_P1 + (size_t)CSPL * N_TOK * 16;   // +1.05 MB
    const size_t OFF_P3   = OFF_P2 + 16ull * FLAG_CAP * 16;       // +2.10 MB
    const size_t NEED     = OFF_P3 + (size_t)CAP2 * 32 * 8;       // +1.05 MB ~= 25.5 MB

    if (ws_size >= NEED) {
        _Float16* zef = (_Float16*)(ws + OFF_ZEF);
        _Float16* cbf = (_Float16*)(ws + OFF_CBF);
        float4* partial  = (float4*)(ws + OFF_P1);
        float4* partial2 = (float4*)(ws + OFF_P2);
        float2* part3    = (float2*)(ws + OFF_P3);

        hipLaunchKernelGGL(k_cnorm, dim3(KC / 4), dim3(256), 0, stream,
                           cb, cnorm, accum, flagc, flagc2, cbf);
        hipLaunchKernelGGL(k_convert_ze, dim3(N_TOK * DD / 8 / 256), dim3(256), 0, stream,
                           ze, zef, N_TOK * DD / 8);
        hipLaunchKernelGGL(k_argmin_f16, dim3(N_TOK / MT, CSPL), dim3(256), 0, stream,
                           zef, cbf, cnorm, partial);
        hipLaunchKernelGGL(k_combine, dim3(N_TOK / 256), dim3(256), 0, stream,
                           partial, idxi, out_idx, flagc, flag_list, CSPL, EPS1, FLAG_CAP);
        hipLaunchKernelGGL(k_argmin2, dim3(FLAG_CAP / 64, 16), dim3(256), 0, stream,
                           ze, cb, cnorm, flag_list, flagc, partial2);
        hipLaunchKernelGGL(k_combine2, dim3(FLAG_CAP / 256), dim3(256), 0, stream,
                           partial2, flag_list, flagc, idxi, out_idx, flagc2, list2);
        hipLaunchKernelGGL(k_rescore_part, dim3(64, 32), dim3(256), 0, stream,
                           ze, cb, cnorm, flagc2, list2, part3, CAP2);
        hipLaunchKernelGGL(k_rescore_fin, dim3(CAP2 / 256), dim3(256), 0, stream,
                           part3, flagc2, list2, idxi, out_idx, CAP2);
    } else {
        hipLaunchKernelGGL(k_cnorm, dim3(KC / 4), dim3(256), 0, stream,
                           cb, cnorm, accum, flagc, flagc2, (_Float16*)0);
        float4* partial = (float4*)d_out;
        int* fl = (int*)(ws + 163856);
        hipLaunchKernelGGL(k_argmin_fb, dim3(N_TOK / MT, 16), dim3(256), 0, stream,
                           ze, cb, cnorm, partial);
        hipLaunchKernelGGL(k_combine, dim3(N_TOK / 256), dim3(256), 0, stream,
                           partial, idxi, out_idx, flagc, fl, 16, EPS2, FLAG_CAP);
        hipLaunchKernelGGL(k_rescore, dim3(128), dim3(256), 0, stream,
                           ze, cb, cnorm, flagc, fl, idxi, out_idx, FLAG_CAP);
    }

    hipLaunchKernelGGL(k_gather, dim3(N_TOK / 16), dim3(256), 0, stream, ze, cb, idxi, out_zq, accum);
    hipLaunchKernelGGL(k_final,  dim3(1), dim3(1), 0, stream, accum, out_loss);
}